// Round 16
// baseline (257.848 us; speedup 1.0000x reference)
//
#include <hip/hip_runtime.h>
#include <cstdint>

typedef unsigned short u16;
typedef unsigned int   u32;
typedef unsigned long long u64;

typedef short bf16x8 __attribute__((ext_vector_type(8)));
typedef float f32x4  __attribute__((ext_vector_type(4)));
typedef u16   u16x8  __attribute__((ext_vector_type(8)));

__device__ __forceinline__ u16 f2b(float f){
  u32 u = __float_as_uint(f);
  u += 0x7FFFu + ((u >> 16) & 1u);
  return (u16)(u >> 16);
}
__device__ __forceinline__ float b2f(u16 h){ return __uint_as_float(((u32)h) << 16); }
__device__ __forceinline__ u32 fkey(float f){
  u32 u = __float_as_uint(f);
  return u ^ ((u & 0x80000000u) ? 0xFFFFFFFFu : 0x80000000u);
}
__device__ __forceinline__ float unkey(u32 k){
  u32 u = (k & 0x80000000u) ? (k ^ 0x80000000u) : ~k;
  return __uint_as_float(u);
}
__device__ __forceinline__ void gload16(const void* g, void* l){
  __builtin_amdgcn_global_load_lds(
      reinterpret_cast<const __attribute__((address_space(1))) char*>(reinterpret_cast<uintptr_t>(g)),
      reinterpret_cast<__attribute__((address_space(3))) char*>(reinterpret_cast<uintptr_t>(l)),
      16, 0, 0);
}

// ---------------- init: per-t-tile kemax + compacted per-XCD work list (4 head groups) ----------------
// list slot k*8+x belongs to XCD x. Entry = tb*64 + sb*4 + hg, or -1. Actives fill front slots.
__global__ __launch_bounds__(256) void k_init(const int* __restrict__ ke, int* __restrict__ list){
  __shared__ int km[64];
  int tid = threadIdx.x;
  if (tid < 64){
    int m = 0;
    for (int j = 0; j < 32; j++) m = max(m, ke[tid * 32 + j]);
    km[tid] = m;
  }
  __syncthreads();
  if (tid < 8){
    int x = tid, n = 0;
    for (int j0 = 0; j0 < 8; j0++){
      int tb = j0 * 8 + x;
      int kmax = km[tb];
      for (int sb = 0; sb < 16; sb++){
        if (sb * 128 < kmax){
          for (int hg = 0; hg < 4; hg++){ list[n * 8 + x] = tb * 64 + sb * 4 + hg; n++; }
        }
      }
    }
    for (; n < 512; n++) list[n * 8 + x] = -1;
  }
}

// ---------------- f32 -> bf16 convert (8 elems/thread) ----------------
__global__ __launch_bounds__(256) void k_cvt(const float* __restrict__ in, u16* __restrict__ out, int n8){
  int i = blockIdx.x * 256 + threadIdx.x;
  if (i >= n8) return;
  const float4* p = (const float4*)in + (size_t)i * 2;
  float4 a = p[0], b = p[1];
  u16x8 v;
  v[0]=f2b(a.x); v[1]=f2b(a.y); v[2]=f2b(a.z); v[3]=f2b(a.w);
  v[4]=f2b(b.x); v[5]=f2b(b.y); v[6]=f2b(b.z); v[7]=f2b(b.w);
  *((u16x8*)out + i) = v;
}

// ---------------- transpose-convert: out[c][r] = bf16(in[r][c]) ----------------
__global__ __launch_bounds__(256) void k_tcvt(const float* __restrict__ in, u16* __restrict__ out, int R, int C){
  __shared__ float tile[32][33];
  int c0 = blockIdx.x * 32, r0 = blockIdx.y * 32;
  int tx = threadIdx.x & 31, ty = threadIdx.x >> 5;   // ty 0..7
  for (int i = 0; i < 4; i++){
    int r = ty * 4 + i;
    tile[r][tx] = in[(size_t)(r0 + r) * C + c0 + tx];
  }
  __syncthreads();
  for (int i = 0; i < 4; i++){
    int c = ty * 4 + i;
    out[(size_t)(c0 + c) * R + r0 + tx] = f2b(tile[tx][c]);
  }
}

// ---------------- build WC^T: out[c][i], c<128 from wk, 128..159 from w_proj, pad 0 ----------------
__global__ __launch_bounds__(256) void k_wct(const float* __restrict__ wk, const float* __restrict__ wp, u16* __restrict__ out){
  __shared__ float tile[32][33];
  int c0 = blockIdx.x * 32, i0 = blockIdx.y * 32;
  int tx = threadIdx.x & 31, ty = threadIdx.x >> 5;
  for (int j = 0; j < 4; j++){
    int i = i0 + ty * 4 + j;
    int c = c0 + tx;
    float v = 0.f;
    if (c < 128) v = wk[(size_t)i * 128 + c];
    else if (c < 160) v = wp[(size_t)i * 32 + (c - 128)];
    tile[ty * 4 + j][tx] = v;  // tile[i_local][c_local]
  }
  __syncthreads();
  for (int j = 0; j < 4; j++){
    int c = c0 + ty * 4 + j;
    out[(size_t)c * 4096 + i0 + tx] = f2b(tile[tx][ty * 4 + j]);
  }
}

// ---------------- GEMM kw partial: kwp[z][2048][192]; swizzled LDS (rule #21c) ----------------
__global__ __launch_bounds__(256) void k_gemm_kw(const float* __restrict__ A, const u16* __restrict__ B, float* __restrict__ Cp){
  const int Kd = 4096, NC = 192;
  __shared__ float As[128 * 64];   // 32KB, f32 staging; 16B chunk slot ^= row&7 (slots 0..15)
  __shared__ u16 Bs[64 * 64];      // 8KB; slot ^= row&7 (slots 0..7)
  int lin = blockIdx.x;
  int xcd = lin & 7, idx = lin >> 3;
  int nb = idx % 3, pz = idx / 3;
  int p = xcd + 8 * pz;            // 0..127
  int m0 = (p & 15) * 128;
  int kt0 = (p >> 4) * 512;
  int n0 = nb * 64;
  float* C = Cp + (size_t)(p >> 4) * 2048 * NC;
  int tid = threadIdx.x, lane = tid & 63, wid = tid >> 6;
  int wm = wid * 32;
  f32x4 acc[2][4] = {};
  for (int kt = kt0; kt < kt0 + 512; kt += 64){
    for (int c = tid; c < 2048; c += 256){
      int row = c >> 4, slot = (c & 15) ^ (row & 7);
      gload16(A + (size_t)(m0 + row) * Kd + kt + slot * 4, (float*)As + (size_t)c * 4);
    }
    for (int c = tid; c < 512; c += 256){
      int row = c >> 3, slot = (c & 7) ^ (row & 7);
      gload16(B + (size_t)(n0 + row) * Kd + kt + slot * 8, (u16*)Bs + (size_t)c * 8);
    }
    __syncthreads();
    for (int kk = 0; kk < 2; kk++){
      bf16x8 af[2], bfr[4];
      for (int i = 0; i < 2; i++){
        int row = wm + i * 16 + (lane & 15);
        int c0 = kk * 8 + (lane >> 4) * 2;  // 16B-chunk index (of 16)
        f32x4 lo = *(const f32x4*)&As[row * 64 + ((c0)     ^ (row & 7)) * 4];
        f32x4 hi = *(const f32x4*)&As[row * 64 + ((c0 + 1) ^ (row & 7)) * 4];
        bf16x8 t;
        t[0]=(short)f2b(lo[0]); t[1]=(short)f2b(lo[1]); t[2]=(short)f2b(lo[2]); t[3]=(short)f2b(lo[3]);
        t[4]=(short)f2b(hi[0]); t[5]=(short)f2b(hi[1]); t[6]=(short)f2b(hi[2]); t[7]=(short)f2b(hi[3]);
        af[i] = t;
      }
      for (int j = 0; j < 4; j++){
        int row = j * 16 + (lane & 15);
        int slot = (kk * 4 + (lane >> 4)) ^ (row & 7);
        bfr[j] = *(const bf16x8*)&Bs[row * 64 + slot * 8];
      }
      for (int i = 0; i < 2; i++)
        for (int j = 0; j < 4; j++)
          acc[i][j] = __builtin_amdgcn_mfma_f32_16x16x32_bf16(af[i], bfr[j], acc[i][j], 0, 0, 0);
    }
    __syncthreads();
  }
  for (int i = 0; i < 2; i++)
    for (int j = 0; j < 4; j++){
      int row = m0 + wm + i * 16 + ((lane >> 4) * 4);
      int col = n0 + j * 16 + (lane & 15);
      for (int r = 0; r < 4; r++)
        C[(size_t)(row + r) * NC + col] = acc[i][j][r];
    }
}

// ---------------- reduce partials + LayerNorm + RoPE -> krot bf16; also wfin[2048][32] f32 ----------------
__global__ __launch_bounds__(256) void k_lnrope(const float* __restrict__ kwp, const float* __restrict__ gamma,
                                                const float* __restrict__ beta, const float* __restrict__ cosp,
                                                const float* __restrict__ sinp, u16* __restrict__ krot,
                                                float* __restrict__ wfin){
  const size_t ZS = (size_t)2048 * 192;
  int row = blockIdx.x * 4 + (threadIdx.x >> 6);
  int lane = threadIdx.x & 63;
  const float* x = kwp + (size_t)row * 192;
  float2 v = {0.f, 0.f};
  for (int z = 0; z < 8; z++){
    float2 p = *(const float2*)&x[z * ZS + lane * 2];
    v.x += p.x; v.y += p.y;
  }
  float s = v.x + v.y, ss = v.x * v.x + v.y * v.y;
  for (int o = 32; o; o >>= 1){ s += __shfl_xor(s, o); ss += __shfl_xor(ss, o); }
  float mu = s * (1.f / 128.f);
  float var = ss * (1.f / 128.f) - mu * mu;
  float rs = rsqrtf(var + 1e-6f);
  float y0 = (v.x - mu) * rs * gamma[lane * 2]     + beta[lane * 2];
  float y1 = (v.y - mu) * rs * gamma[lane * 2 + 1] + beta[lane * 2 + 1];
  u16* out = krot + (size_t)row * 128;
  if (lane < 32){
    float c = cosp[(size_t)row * 64 + lane], sn = sinp[(size_t)row * 64 + lane];
    out[lane]      = f2b(y0 * c - y1 * sn);
    out[lane + 32] = f2b(y1 * c + y0 * sn);
    float wsum = 0.f;
    for (int z = 0; z < 8; z++) wsum += x[z * ZS + 128 + lane];
    wfin[(size_t)row * 32 + lane] = wsum;
  } else {
    out[lane * 2]     = f2b(y0);
    out[lane * 2 + 1] = f2b(y1);
  }
}

// ---------------- GEMM q + fused RoPE epilogue; swizzled LDS (rule #21c) ----------------
__global__ __launch_bounds__(256) void k_gemm_q(const u16* __restrict__ A, const u16* __restrict__ B,
                                                const float* __restrict__ cosp, const float* __restrict__ sinp,
                                                u16* __restrict__ C){
  const int N = 4096, Kd = 1536;
  __shared__ u16 As[128 * 64];
  __shared__ u16 Bs[128 * 64];
  int linb = blockIdx.x;                   // 512 blocks
  int xcd = linb & 7, loc = linb >> 3;     // 64 per XCD
  int n0 = (xcd * 4 + (loc >> 4)) * 128;   // 4 n-panels per XCD -> B slice L2-resident
  int m0 = (loc & 15) * 128;
  int tid = threadIdx.x, lane = tid & 63, wid = tid >> 6;
  int wm = (wid >> 1) * 64, wn = (wid & 1) * 64;
  f32x4 acc[4][4] = {};
  for (int kt = 0; kt < Kd; kt += 64){
    for (int c = tid; c < 1024; c += 256){
      int row = c >> 3, slot = (c & 7) ^ (row & 7);
      gload16(A + (size_t)(m0 + row) * Kd + kt + slot * 8, (u16*)As + (size_t)c * 8);
      gload16(B + (size_t)(n0 + row) * Kd + kt + slot * 8, (u16*)Bs + (size_t)c * 8);
    }
    __syncthreads();
    for (int kk = 0; kk < 2; kk++){
      bf16x8 af[4], bfr[4];
      for (int i = 0; i < 4; i++){
        int rowa = wm + i * 16 + (lane & 15);
        int rowb = wn + i * 16 + (lane & 15);
        int sa = (kk * 4 + (lane >> 4)) ^ (rowa & 7);
        int sbx = (kk * 4 + (lane >> 4)) ^ (rowb & 7);
        af[i]  = *(const bf16x8*)&As[rowa * 64 + sa * 8];
        bfr[i] = *(const bf16x8*)&Bs[rowb * 64 + sbx * 8];
      }
      for (int i = 0; i < 4; i++)
        for (int j = 0; j < 4; j++)
          acc[i][j] = __builtin_amdgcn_mfma_f32_16x16x32_bf16(af[i], bfr[j], acc[i][j], 0, 0, 0);
    }
    __syncthreads();
  }
  // fused RoPE: wn==0 waves hold dims 0..63 of each head (n0 = head base, 128-wide)
  if (wn == 0){
    int l = lane & 15;
    int base = lane & 48;
    int sl = base + ((2 * l) & 15);
    for (int i = 0; i < 4; i++){
      int rowb = m0 + wm + i * 16 + ((lane >> 4) * 4);
      f32x4 ne[4];
      for (int j = 0; j < 4; j++){
        int jj = j & 1;
        for (int r = 0; r < 4; r++){
          float eA = __shfl(acc[i][2 * jj][r],     sl);
          float eB = __shfl(acc[i][2 * jj + 1][r], sl);
          float oA = __shfl(acc[i][2 * jj][r],     sl + 1);
          float oB = __shfl(acc[i][2 * jj + 1][r], sl + 1);
          float e = (l >= 8) ? eB : eA;
          float o = (l >= 8) ? oB : oA;
          int row = rowb + r;
          int d = j * 16 + l;
          float c = cosp[(size_t)row * 64 + d];
          float s = sinp[(size_t)row * 64 + d];
          ne[j][r] = (j < 2) ? (e * c - o * s) : (o * c + e * s);
        }
      }
      for (int j = 0; j < 4; j++) acc[i][j] = ne[j];
    }
  }
  for (int i = 0; i < 4; i++)
    for (int j = 0; j < 4; j++){
      int row = m0 + wm + i * 16 + ((lane >> 4) * 4);
      int col = n0 + wn + j * 16 + (lane & 15);
      for (int r = 0; r < 4; r++)
        C[(size_t)(row + r) * N + col] = f2b(acc[i][j][r]);
    }
}

// ---------------- scores v16: 4 head groups of 8 (tail amortization); bf16 partials ----------------
__global__ __launch_bounds__(256, 4) void k_scores(const u16* __restrict__ q, const u16* __restrict__ krot,
                                                   const float* __restrict__ wfin, const int* __restrict__ list,
                                                   u16* __restrict__ Sb0, u16* __restrict__ Sb1,
                                                   u16* __restrict__ Sb2, u16* __restrict__ Sb3){
  __shared__ u16 Bs[128 * 128];     // krot panel (32KB); 16B slot ^= row&7
  __shared__ float Ws[8][32];       // Ws[h][r] for this head group
  int e = list[blockIdx.x];
  if (e < 0) return;
  int tb = e >> 6, sb = (e >> 2) & 15, hg = e & 3;
  int t0 = tb * 32, s0 = sb * 128;
  int tid = threadIdx.x, lane = tid & 63, wid = tid >> 6;
  int wr = wid >> 1, wc = wid & 1;  // wave = 16(t) x 64(s) subtile

  for (int c = tid; c < 2048; c += 256){
    int row = c >> 4, slot = (c & 15) ^ (row & 7);
    gload16(krot + (size_t)(s0 + row) * 128 + slot * 8, (u16*)Bs + (size_t)c * 8);
  }
  if (tid < 256){
    int h = tid >> 5, r = tid & 31;
    if (h < 8) Ws[h][r] = wfin[(size_t)(t0 + r) * 32 + hg * 8 + h];
  }
  __syncthreads();

  // hoist B fragments (head-invariant): 16 x b128, one-time swizzled LDS reads
  bf16x8 bfr[4][4];
#pragma unroll
  for (int j = 0; j < 4; j++)
#pragma unroll
    for (int kc = 0; kc < 4; kc++){
      int row = wc * 64 + j * 16 + (lane & 15);
      int slot = (kc * 4 + (lane >> 4)) ^ (row & 7);
      bfr[j][kc] = *(const bf16x8*)&Bs[row * 128 + slot * 8];
    }

  f32x4 acc[4] = {};
  const u16* qbase = q + ((size_t)t0 + wr * 16 + (lane & 15)) * 4096 + (size_t)hg * 8 * 128 + (lane >> 4) * 8;
  int rbase = wr * 16 + ((lane >> 4) * 4);
#pragma unroll
  for (int h = 0; h < 8; h++){
    bf16x8 af[4];
#pragma unroll
    for (int kc = 0; kc < 4; kc++)
      af[kc] = *(const bf16x8*)&qbase[h * 128 + kc * 32];
    f32x4 ah[4] = {};
#pragma unroll
    for (int kc = 0; kc < 4; kc++)
#pragma unroll
      for (int j = 0; j < 4; j++)
        ah[j] = __builtin_amdgcn_mfma_f32_16x16x32_bf16(af[kc], bfr[j][kc], ah[j], 0, 0, 0);
#pragma unroll
    for (int r = 0; r < 4; r++){
      float wv = Ws[h][rbase + r];
#pragma unroll
      for (int j = 0; j < 4; j++)
        acc[j][r] += fmaxf(ah[j][r], 0.f) * wv;
    }
  }
  u16* Sp = (hg == 0) ? Sb0 : (hg == 1) ? Sb1 : (hg == 2) ? Sb2 : Sb3;
#pragma unroll
  for (int j = 0; j < 4; j++){
    int col = s0 + wc * 64 + j * 16 + (lane & 15);
#pragma unroll
    for (int r = 0; r < 4; r++)
      Sp[(size_t)(t0 + rbase + r) * 2048 + col] = f2b(acc[j][r]);   // bf16 raw partial
  }
}

// ---------------- per-row top-K: sums 4 bf16 partials, applies scale, synthesizes masked keys ----------------
__global__ __launch_bounds__(256) void k_topk(const u16* __restrict__ Sb0, const u16* __restrict__ Sb1,
                                              const u16* __restrict__ Sb2, const u16* __restrict__ Sb3,
                                              const int* __restrict__ ktp, const int* __restrict__ ksv,
                                              const int* __restrict__ ke, float* __restrict__ out){
  int t = blockIdx.x;
  int T = gridDim.x;
  const u16* r0 = Sb0 + (size_t)t * 2048;
  const u16* r1 = Sb1 + (size_t)t * 2048;
  const u16* r2 = Sb2 + (size_t)t * 2048;
  const u16* r3 = Sb3 + (size_t)t * 2048;
  __shared__ u32 keys[2048];
  __shared__ u32 hist[256];
  __shared__ u32 ssum[256];
  __shared__ u32 sb, srem;
  __shared__ u32 wtot[8];
  __shared__ int selIdx[256];
  __shared__ u32 baseGt, baseTie;
  __shared__ u64 skey[256];
  int tid = threadIdx.x;
  int K = ktp[0]; if (K > 256) K = 256;
  int ket = ke[t]; if (ket < 0) ket = 0; if (ket > 2048) ket = 2048;
  int kst = ksv[t]; if (kst < 0) kst = 0;
  int limit = (ket + 255) & ~255;
  if (limit < 256) limit = 256;
  if (limit > 2048) limit = 2048;
  const u32 kneg = fkey(-1e30f);
  const float scale = 0.015625f;  // 1/sqrt(D*H) = 1/64
  for (int i8 = tid; i8 < (limit >> 3); i8 += 256){
    int base = i8 * 8;
    u16x8 a = ((const u16x8*)r0)[i8];
    u16x8 b = ((const u16x8*)r1)[i8];
    u16x8 c = ((const u16x8*)r2)[i8];
    u16x8 d = ((const u16x8*)r3)[i8];
#pragma unroll
    for (int e = 0; e < 8; e++){
      int i = base + e;
      float v = (b2f(a[e]) + b2f(b[e]) + b2f(c[e]) + b2f(d[e])) * scale;
      keys[i] = (i >= kst && i < ket) ? fkey(v) : kneg;
    }
  }
  __syncthreads();
  if (limit > K){
    u32 prefix = 0, pmask = 0, rem = (u32)K;
    for (int p = 3; p >= 0; p--){
      int sh = p * 8;
      hist[tid] = 0;
      __syncthreads();
      for (int i = tid; i < limit; i += 256){
        u32 u = keys[i];
        if ((u & pmask) == prefix) atomicAdd(&hist[(u >> sh) & 255], 1u);
      }
      __syncthreads();
      ssum[tid] = hist[tid];
      __syncthreads();
      for (int off = 1; off < 256; off <<= 1){
        u32 add = (tid + off < 256) ? ssum[tid + off] : 0u;
        __syncthreads();
        ssum[tid] += add;
        __syncthreads();
      }
      u32 mine = ssum[tid];
      u32 above = (tid == 255) ? 0u : ssum[tid + 1];
      if (mine >= rem && above < rem){ sb = (u32)tid; srem = rem - above; }
      __syncthreads();
      prefix |= (sb << sh);
      pmask |= (255u << sh);
      rem = srem;
      __syncthreads();
    }
    u32 thr = prefix;
    int G = K - (int)rem;
    if (tid == 0){ baseGt = 0; baseTie = 0; }
    __syncthreads();
    int nch = limit >> 8;
    for (int ch = 0; ch < nch; ch++){
      int i = ch * 256 + tid;
      u32 u = keys[i];
      bool gt = (u > thr), tie = (u == thr);
      u64 bg = __ballot(gt), bt = __ballot(tie);
      int lane = tid & 63, w = tid >> 6;
      if (lane == 0){ wtot[w] = (u32)__popcll(bg); wtot[4 + w] = (u32)__popcll(bt); }
      __syncthreads();
      u32 og = baseGt, ot = baseTie;
      for (int ww = 0; ww < w; ww++){ og += wtot[ww]; ot += wtot[4 + ww]; }
      og += (u32)__popcll(bg & ((1ull << lane) - 1ull));
      ot += (u32)__popcll(bt & ((1ull << lane) - 1ull));
      if (gt) selIdx[og] = i;
      else if (tie && ot < rem) selIdx[G + ot] = i;
      __syncthreads();
      if (tid == 0){
        for (int ww = 0; ww < 4; ww++){ baseGt += wtot[ww]; baseTie += wtot[4 + ww]; }
      }
      __syncthreads();
    }
    if (tid < K){
      int si = selIdx[tid];
      u32 u = keys[si];
      skey[tid] = ((u64)(~u) << 32) | (u32)si;   // value desc, idx asc
    } else {
      skey[tid] = ~0ull;
    }
  } else {
    if (tid < K) skey[tid] = ((u64)(~keys[tid]) << 32) | (u32)tid;
    else skey[tid] = ~0ull;
  }
  __syncthreads();
  for (int size = 2; size <= 256; size <<= 1){
    for (int stride = size >> 1; stride > 0; stride >>= 1){
      int p = tid ^ stride;
      if (p > tid){
        bool up = ((tid & size) == 0);
        u64 a = skey[tid], b = skey[p];
        if ((a > b) == up){ skey[tid] = b; skey[p] = a; }
      }
      __syncthreads();
    }
  }
  if (tid < K){
    u64 sk = skey[tid];
    int idx = (int)(u32)(sk & 0xFFFFFFFFu);
    float val = unkey(~(u32)(sk >> 32));
    out[(size_t)t * K + tid] = (float)idx;                      // idx chunk (as float)
    out[(size_t)T * K + (size_t)t * K + tid] = val;             // values chunk
  }
}

extern "C" void kernel_launch(void* const* d_in, const int* in_sizes, int n_in,
                              void* d_out, int out_size, void* d_ws, size_t ws_size,
                              hipStream_t stream){
  const float* hs   = (const float*)d_in[0];
  const float* ql   = (const float*)d_in[1];
  const int*   ks   = (const int*)  d_in[2];
  const int*   ke   = (const int*)  d_in[3];
  const float* cosp = (const float*)d_in[4];
  const float* sinp = (const float*)d_in[5];
  const float* wqb  = (const float*)d_in[6];
  const float* wk   = (const float*)d_in[7];
  const float* kg   = (const float*)d_in[8];
  const float* kb   = (const float*)d_in[9];
  const float* wp   = (const float*)d_in[10];
  const int*   ktp  = (const int*)  d_in[11];

  char* w = (char*)d_ws;
  u16* qlb = (u16*)w;  w += (size_t)2048 * 1536 * 2;   // [0, 6.29MB)
  u16* wqT = (u16*)w;  w += (size_t)4096 * 1536 * 2;   // [6.29, 18.87MB)
  u16* wct = (u16*)w;  w += (size_t)192 * 4096 * 2;
  u16* qb  = (u16*)w;  w += (size_t)2048 * 4096 * 2;
  float* kwp = (float*)w; w += (size_t)8 * 2048 * 192 * 4;
  float* wfin = (float*)w; w += (size_t)2048 * 32 * 4;
  u16* krt = (u16*)w;  w += (size_t)2048 * 128 * 2;
  u16* Sb0 = (u16*)w;  w += (size_t)2048 * 2048 * 2;   // bf16 partials
  u16* Sb1 = (u16*)w;  w += (size_t)2048 * 2048 * 2;
  int* list = (int*)w; w += 4096 * 4;
  // Sb2/Sb3 alias qlb+wqT (2x8.39MB = 16.78MB <= 18.87MB): lifetime-disjoint —
  // gemm_q finishes reading qlb/wqT before k_scores writes; cvt/tcvt rewrite next call.
  u16* Sb2 = (u16*)d_ws;
  u16* Sb3 = (u16*)((char*)d_ws + (size_t)2048 * 2048 * 2);

  hipLaunchKernelGGL(k_init, dim3(1), dim3(256), 0, stream, ke, list);
  hipLaunchKernelGGL(k_cvt, dim3(1536), dim3(256), 0, stream, ql, qlb, 393216);
  hipLaunchKernelGGL(k_tcvt, dim3(128, 48), dim3(256), 0, stream, wqb, wqT, 1536, 4096);
  hipLaunchKernelGGL(k_wct, dim3(6, 128), dim3(256), 0, stream, wk, wp, wct);
  hipLaunchKernelGGL(k_gemm_kw, dim3(384), dim3(256), 0, stream, hs, wct, kwp);
  hipLaunchKernelGGL(k_lnrope, dim3(512), dim3(256), 0, stream, kwp, kg, kb, cosp, sinp, krt, wfin);
  hipLaunchKernelGGL(k_gemm_q, dim3(512), dim3(256), 0, stream, qlb, wqT, cosp, sinp, qb);
  hipLaunchKernelGGL(k_scores, dim3(4096), dim3(256), 0, stream, qb, krt, wfin, list, Sb0, Sb1, Sb2, Sb3);
  hipLaunchKernelGGL(k_topk, dim3(2048), dim3(256), 0, stream, Sb0, Sb1, Sb2, Sb3, ktp, ks, ke, (float*)d_out);
}

// Round 17
// 175.852 us; speedup vs baseline: 1.4663x; 1.4663x over previous
//
#include <hip/hip_runtime.h>
#include <cstdint>

typedef unsigned short u16;
typedef unsigned int   u32;
typedef unsigned long long u64;

typedef short bf16x8 __attribute__((ext_vector_type(8)));
typedef float f32x4  __attribute__((ext_vector_type(4)));
typedef u16   u16x8  __attribute__((ext_vector_type(8)));

__device__ __forceinline__ u16 f2b(float f){
  u32 u = __float_as_uint(f);
  u += 0x7FFFu + ((u >> 16) & 1u);
  return (u16)(u >> 16);
}
__device__ __forceinline__ float b2f(u16 h){ return __uint_as_float(((u32)h) << 16); }
__device__ __forceinline__ u32 fkey(float f){
  u32 u = __float_as_uint(f);
  return u ^ ((u & 0x80000000u) ? 0xFFFFFFFFu : 0x80000000u);
}
__device__ __forceinline__ float unkey(u32 k){
  u32 u = (k & 0x80000000u) ? (k ^ 0x80000000u) : ~k;
  return __uint_as_float(u);
}
__device__ __forceinline__ void gload16(const void* g, void* l){
  __builtin_amdgcn_global_load_lds(
      reinterpret_cast<const __attribute__((address_space(1))) char*>(reinterpret_cast<uintptr_t>(g)),
      reinterpret_cast<__attribute__((address_space(3))) char*>(reinterpret_cast<uintptr_t>(l)),
      16, 0, 0);
}

// ---------------- init: compacted per-XCD work list (2 head groups) + per-XCD queue counters ----------------
// list slot n*8+x belongs to XCD x. Entry = tb*32 + sb*2 + hgrp, or -1. Actives fill front slots.
__global__ __launch_bounds__(256) void k_init(const int* __restrict__ ke, int* __restrict__ list, int* __restrict__ qcnt){
  __shared__ int km[64];
  int tid = threadIdx.x;
  if (tid < 64){
    int m = 0;
    for (int j = 0; j < 32; j++) m = max(m, ke[tid * 32 + j]);
    km[tid] = m;
  }
  __syncthreads();
  if (tid < 8){
    int x = tid, n = 0;
    for (int j0 = 0; j0 < 8; j0++){
      int tb = j0 * 8 + x;
      int kmax = km[tb];
      for (int sb = 0; sb < 16; sb++){
        if (sb * 128 < kmax){
          list[n * 8 + x] = tb * 32 + sb * 2 + 0; n++;
          list[n * 8 + x] = tb * 32 + sb * 2 + 1; n++;
        }
      }
    }
    for (; n < 256; n++) list[n * 8 + x] = -1;
    qcnt[x] = 0;
  }
}

// ---------------- f32 -> bf16 convert (8 elems/thread) ----------------
__global__ __launch_bounds__(256) void k_cvt(const float* __restrict__ in, u16* __restrict__ out, int n8){
  int i = blockIdx.x * 256 + threadIdx.x;
  if (i >= n8) return;
  const float4* p = (const float4*)in + (size_t)i * 2;
  float4 a = p[0], b = p[1];
  u16x8 v;
  v[0]=f2b(a.x); v[1]=f2b(a.y); v[2]=f2b(a.z); v[3]=f2b(a.w);
  v[4]=f2b(b.x); v[5]=f2b(b.y); v[6]=f2b(b.z); v[7]=f2b(b.w);
  *((u16x8*)out + i) = v;
}

// ---------------- transpose-convert: out[c][r] = bf16(in[r][c]) ----------------
__global__ __launch_bounds__(256) void k_tcvt(const float* __restrict__ in, u16* __restrict__ out, int R, int C){
  __shared__ float tile[32][33];
  int c0 = blockIdx.x * 32, r0 = blockIdx.y * 32;
  int tx = threadIdx.x & 31, ty = threadIdx.x >> 5;   // ty 0..7
  for (int i = 0; i < 4; i++){
    int r = ty * 4 + i;
    tile[r][tx] = in[(size_t)(r0 + r) * C + c0 + tx];
  }
  __syncthreads();
  for (int i = 0; i < 4; i++){
    int c = ty * 4 + i;
    out[(size_t)(c0 + c) * R + r0 + tx] = f2b(tile[tx][c]);
  }
}

// ---------------- build WC^T: out[c][i], c<128 from wk, 128..159 from w_proj, pad 0 ----------------
__global__ __launch_bounds__(256) void k_wct(const float* __restrict__ wk, const float* __restrict__ wp, u16* __restrict__ out){
  __shared__ float tile[32][33];
  int c0 = blockIdx.x * 32, i0 = blockIdx.y * 32;
  int tx = threadIdx.x & 31, ty = threadIdx.x >> 5;
  for (int j = 0; j < 4; j++){
    int i = i0 + ty * 4 + j;
    int c = c0 + tx;
    float v = 0.f;
    if (c < 128) v = wk[(size_t)i * 128 + c];
    else if (c < 160) v = wp[(size_t)i * 32 + (c - 128)];
    tile[ty * 4 + j][tx] = v;  // tile[i_local][c_local]
  }
  __syncthreads();
  for (int j = 0; j < 4; j++){
    int c = c0 + ty * 4 + j;
    out[(size_t)c * 4096 + i0 + tx] = f2b(tile[tx][ty * 4 + j]);
  }
}

// ---------------- GEMM kw partial: kwp[z][2048][192]; swizzled LDS (rule #21c) ----------------
__global__ __launch_bounds__(256) void k_gemm_kw(const float* __restrict__ A, const u16* __restrict__ B, float* __restrict__ Cp){
  const int Kd = 4096, NC = 192;
  __shared__ float As[128 * 64];   // 32KB, f32 staging; 16B chunk slot ^= row&7 (slots 0..15)
  __shared__ u16 Bs[64 * 64];      // 8KB; slot ^= row&7 (slots 0..7)
  int lin = blockIdx.x;
  int xcd = lin & 7, idx = lin >> 3;
  int nb = idx % 3, pz = idx / 3;
  int p = xcd + 8 * pz;            // 0..127
  int m0 = (p & 15) * 128;
  int kt0 = (p >> 4) * 512;
  int n0 = nb * 64;
  float* C = Cp + (size_t)(p >> 4) * 2048 * NC;
  int tid = threadIdx.x, lane = tid & 63, wid = tid >> 6;
  int wm = wid * 32;
  f32x4 acc[2][4] = {};
  for (int kt = kt0; kt < kt0 + 512; kt += 64){
    for (int c = tid; c < 2048; c += 256){
      int row = c >> 4, slot = (c & 15) ^ (row & 7);
      gload16(A + (size_t)(m0 + row) * Kd + kt + slot * 4, (float*)As + (size_t)c * 4);
    }
    for (int c = tid; c < 512; c += 256){
      int row = c >> 3, slot = (c & 7) ^ (row & 7);
      gload16(B + (size_t)(n0 + row) * Kd + kt + slot * 8, (u16*)Bs + (size_t)c * 8);
    }
    __syncthreads();
    for (int kk = 0; kk < 2; kk++){
      bf16x8 af[2], bfr[4];
      for (int i = 0; i < 2; i++){
        int row = wm + i * 16 + (lane & 15);
        int c0 = kk * 8 + (lane >> 4) * 2;  // 16B-chunk index (of 16)
        f32x4 lo = *(const f32x4*)&As[row * 64 + ((c0)     ^ (row & 7)) * 4];
        f32x4 hi = *(const f32x4*)&As[row * 64 + ((c0 + 1) ^ (row & 7)) * 4];
        bf16x8 t;
        t[0]=(short)f2b(lo[0]); t[1]=(short)f2b(lo[1]); t[2]=(short)f2b(lo[2]); t[3]=(short)f2b(lo[3]);
        t[4]=(short)f2b(hi[0]); t[5]=(short)f2b(hi[1]); t[6]=(short)f2b(hi[2]); t[7]=(short)f2b(hi[3]);
        af[i] = t;
      }
      for (int j = 0; j < 4; j++){
        int row = j * 16 + (lane & 15);
        int slot = (kk * 4 + (lane >> 4)) ^ (row & 7);
        bfr[j] = *(const bf16x8*)&Bs[row * 64 + slot * 8];
      }
      for (int i = 0; i < 2; i++)
        for (int j = 0; j < 4; j++)
          acc[i][j] = __builtin_amdgcn_mfma_f32_16x16x32_bf16(af[i], bfr[j], acc[i][j], 0, 0, 0);
    }
    __syncthreads();
  }
  for (int i = 0; i < 2; i++)
    for (int j = 0; j < 4; j++){
      int row = m0 + wm + i * 16 + ((lane >> 4) * 4);
      int col = n0 + j * 16 + (lane & 15);
      for (int r = 0; r < 4; r++)
        C[(size_t)(row + r) * NC + col] = acc[i][j][r];
    }
}

// ---------------- reduce partials + LayerNorm + RoPE -> krot bf16; also wfin[2048][32] f32 ----------------
__global__ __launch_bounds__(256) void k_lnrope(const float* __restrict__ kwp, const float* __restrict__ gamma,
                                                const float* __restrict__ beta, const float* __restrict__ cosp,
                                                const float* __restrict__ sinp, u16* __restrict__ krot,
                                                float* __restrict__ wfin){
  const size_t ZS = (size_t)2048 * 192;
  int row = blockIdx.x * 4 + (threadIdx.x >> 6);
  int lane = threadIdx.x & 63;
  const float* x = kwp + (size_t)row * 192;
  float2 v = {0.f, 0.f};
  for (int z = 0; z < 8; z++){
    float2 p = *(const float2*)&x[z * ZS + lane * 2];
    v.x += p.x; v.y += p.y;
  }
  float s = v.x + v.y, ss = v.x * v.x + v.y * v.y;
  for (int o = 32; o; o >>= 1){ s += __shfl_xor(s, o); ss += __shfl_xor(ss, o); }
  float mu = s * (1.f / 128.f);
  float var = ss * (1.f / 128.f) - mu * mu;
  float rs = rsqrtf(var + 1e-6f);
  float y0 = (v.x - mu) * rs * gamma[lane * 2]     + beta[lane * 2];
  float y1 = (v.y - mu) * rs * gamma[lane * 2 + 1] + beta[lane * 2 + 1];
  u16* out = krot + (size_t)row * 128;
  if (lane < 32){
    float c = cosp[(size_t)row * 64 + lane], sn = sinp[(size_t)row * 64 + lane];
    out[lane]      = f2b(y0 * c - y1 * sn);
    out[lane + 32] = f2b(y1 * c + y0 * sn);
    float wsum = 0.f;
    for (int z = 0; z < 8; z++) wsum += x[z * ZS + 128 + lane];
    wfin[(size_t)row * 32 + lane] = wsum;
  } else {
    out[lane * 2]     = f2b(y0);
    out[lane * 2 + 1] = f2b(y1);
  }
}

// ---------------- GEMM q + fused RoPE epilogue; swizzled LDS (rule #21c) ----------------
__global__ __launch_bounds__(256) void k_gemm_q(const u16* __restrict__ A, const u16* __restrict__ B,
                                                const float* __restrict__ cosp, const float* __restrict__ sinp,
                                                u16* __restrict__ C){
  const int N = 4096, Kd = 1536;
  __shared__ u16 As[128 * 64];
  __shared__ u16 Bs[128 * 64];
  int linb = blockIdx.x;                   // 512 blocks
  int xcd = linb & 7, loc = linb >> 3;     // 64 per XCD
  int n0 = (xcd * 4 + (loc >> 4)) * 128;   // 4 n-panels per XCD -> B slice L2-resident
  int m0 = (loc & 15) * 128;
  int tid = threadIdx.x, lane = tid & 63, wid = tid >> 6;
  int wm = (wid >> 1) * 64, wn = (wid & 1) * 64;
  f32x4 acc[4][4] = {};
  for (int kt = 0; kt < Kd; kt += 64){
    for (int c = tid; c < 1024; c += 256){
      int row = c >> 3, slot = (c & 7) ^ (row & 7);
      gload16(A + (size_t)(m0 + row) * Kd + kt + slot * 8, (u16*)As + (size_t)c * 8);
      gload16(B + (size_t)(n0 + row) * Kd + kt + slot * 8, (u16*)Bs + (size_t)c * 8);
    }
    __syncthreads();
    for (int kk = 0; kk < 2; kk++){
      bf16x8 af[4], bfr[4];
      for (int i = 0; i < 4; i++){
        int rowa = wm + i * 16 + (lane & 15);
        int rowb = wn + i * 16 + (lane & 15);
        int sa = (kk * 4 + (lane >> 4)) ^ (rowa & 7);
        int sbx = (kk * 4 + (lane >> 4)) ^ (rowb & 7);
        af[i]  = *(const bf16x8*)&As[rowa * 64 + sa * 8];
        bfr[i] = *(const bf16x8*)&Bs[rowb * 64 + sbx * 8];
      }
      for (int i = 0; i < 4; i++)
        for (int j = 0; j < 4; j++)
          acc[i][j] = __builtin_amdgcn_mfma_f32_16x16x32_bf16(af[i], bfr[j], acc[i][j], 0, 0, 0);
    }
    __syncthreads();
  }
  // fused RoPE: wn==0 waves hold dims 0..63 of each head (n0 = head base, 128-wide)
  if (wn == 0){
    int l = lane & 15;
    int base = lane & 48;
    int sl = base + ((2 * l) & 15);
    for (int i = 0; i < 4; i++){
      int rowb = m0 + wm + i * 16 + ((lane >> 4) * 4);
      f32x4 ne[4];
      for (int j = 0; j < 4; j++){
        int jj = j & 1;
        for (int r = 0; r < 4; r++){
          float eA = __shfl(acc[i][2 * jj][r],     sl);
          float eB = __shfl(acc[i][2 * jj + 1][r], sl);
          float oA = __shfl(acc[i][2 * jj][r],     sl + 1);
          float oB = __shfl(acc[i][2 * jj + 1][r], sl + 1);
          float e = (l >= 8) ? eB : eA;
          float o = (l >= 8) ? oB : oA;
          int row = rowb + r;
          int d = j * 16 + l;
          float c = cosp[(size_t)row * 64 + d];
          float s = sinp[(size_t)row * 64 + d];
          ne[j][r] = (j < 2) ? (e * c - o * s) : (o * c + e * s);
        }
      }
      for (int j = 0; j < 4; j++) acc[i][j] = ne[j];
    }
  }
  for (int i = 0; i < 4; i++)
    for (int j = 0; j < 4; j++){
      int row = m0 + wm + i * 16 + ((lane >> 4) * 4);
      int col = n0 + wn + j * 16 + (lane & 15);
      for (int r = 0; r < 4; r++)
        C[(size_t)(row + r) * N + col] = f2b(acc[i][j][r]);
    }
}

// ---------------- scores v17: R14 body + persistent blocks w/ per-XCD queues (tail amortization) ----------------
__global__ __launch_bounds__(256, 4) void k_scores(const u16* __restrict__ q, const u16* __restrict__ krot,
                                                   const float* __restrict__ wfin, const int* __restrict__ list,
                                                   int* __restrict__ qcnt,
                                                   float* __restrict__ S0, float* __restrict__ S1){
  __shared__ u16 Bs[128 * 128];     // krot panel (32KB); 16B slot ^= row&7
  __shared__ float Ws[16][32];      // Ws[h][r] for this head group
  __shared__ int qh;
  int xcd = blockIdx.x & 7;         // 1024 blocks; CP round-robins blocks across XCDs
  int tid = threadIdx.x, lane = tid & 63, wid = tid >> 6;
  int wr = wid >> 1, wc = wid & 1;  // wave = 16(t) x 64(s) subtile
  for (;;){
    if (tid == 0) qh = atomicAdd(&qcnt[xcd], 1);
    __syncthreads();                // broadcasts qh; also guards Bs write-after-read
    int n = qh;
    if (n >= 256) break;
    int e = list[n * 8 + xcd];
    if (e < 0) break;
    int tb = e >> 5, sb = (e >> 1) & 15, hgrp = e & 1;
    int t0 = tb * 32, s0 = sb * 128;

    for (int c = tid; c < 2048; c += 256){
      int row = c >> 4, slot = (c & 15) ^ (row & 7);
      gload16(krot + (size_t)(s0 + row) * 128 + slot * 8, (u16*)Bs + (size_t)c * 8);
    }
    for (int i = tid; i < 512; i += 256){
      int h = i >> 5, r = i & 31;
      Ws[h][r] = wfin[(size_t)(t0 + r) * 32 + hgrp * 16 + h];
    }
    __syncthreads();

    // hoist B fragments (head-invariant): 16 x b128, one-time swizzled LDS reads
    bf16x8 bfr[4][4];
    for (int j = 0; j < 4; j++)
      for (int kc = 0; kc < 4; kc++){
        int row = wc * 64 + j * 16 + (lane & 15);
        int slot = (kc * 4 + (lane >> 4)) ^ (row & 7);
        bfr[j][kc] = *(const bf16x8*)&Bs[row * 128 + slot * 8];
      }

    f32x4 acc[4] = {};
    const u16* qbase = q + ((size_t)t0 + wr * 16 + (lane & 15)) * 4096 + (size_t)hgrp * 16 * 128 + (lane >> 4) * 8;
    int rbase = wr * 16 + ((lane >> 4) * 4);
    for (int h = 0; h < 16; h++){
      bf16x8 af[4];
      for (int kc = 0; kc < 4; kc++)
        af[kc] = *(const bf16x8*)&qbase[h * 128 + kc * 32];
      f32x4 ah[4] = {};
      for (int kc = 0; kc < 4; kc++)
        for (int j = 0; j < 4; j++)
          ah[j] = __builtin_amdgcn_mfma_f32_16x16x32_bf16(af[kc], bfr[j][kc], ah[j], 0, 0, 0);
      for (int r = 0; r < 4; r++){
        float wv = Ws[h][rbase + r];
        for (int j = 0; j < 4; j++)
          acc[j][r] += fmaxf(ah[j][r], 0.f) * wv;
      }
    }
    float* Sp = hgrp ? S1 : S0;
    for (int j = 0; j < 4; j++){
      int col = s0 + wc * 64 + j * 16 + (lane & 15);
      for (int r = 0; r < 4; r++)
        Sp[(size_t)(t0 + rbase + r) * 2048 + col] = acc[j][r];
    }
  }
}

// ---------------- per-row top-K: sums partials, applies scale, synthesizes masked keys ----------------
__global__ __launch_bounds__(256) void k_topk(const float* __restrict__ S0, const float* __restrict__ S1,
                                              const int* __restrict__ ktp, const int* __restrict__ ksv,
                                              const int* __restrict__ ke, float* __restrict__ out){
  int t = blockIdx.x;
  int T = gridDim.x;
  const float* r0 = S0 + (size_t)t * 2048;
  const float* r1 = S1 + (size_t)t * 2048;
  __shared__ u32 keys[2048];
  __shared__ u32 hist[256];
  __shared__ u32 ssum[256];
  __shared__ u32 sb, srem;
  __shared__ u32 wtot[8];
  __shared__ int selIdx[256];
  __shared__ u32 baseGt, baseTie;
  __shared__ u64 skey[256];
  int tid = threadIdx.x;
  int K = ktp[0]; if (K > 256) K = 256;
  int ket = ke[t]; if (ket < 0) ket = 0; if (ket > 2048) ket = 2048;
  int kst = ksv[t]; if (kst < 0) kst = 0;
  int limit = (ket + 255) & ~255;
  if (limit < 256) limit = 256;
  if (limit > 2048) limit = 2048;
  const u32 kneg = fkey(-1e30f);
  const float scale = 0.015625f;  // 1/sqrt(D*H) = 1/64
  for (int i4 = tid; i4 < (limit >> 2); i4 += 256){
    int base = i4 * 4;
    float4 a = ((const float4*)r0)[i4];
    float4 b = ((const float4*)r1)[i4];
    float v0 = (a.x + b.x) * scale, v1 = (a.y + b.y) * scale;
    float v2 = (a.z + b.z) * scale, v3 = (a.w + b.w) * scale;
    keys[base + 0] = (base + 0 >= kst && base + 0 < ket) ? fkey(v0) : kneg;
    keys[base + 1] = (base + 1 >= kst && base + 1 < ket) ? fkey(v1) : kneg;
    keys[base + 2] = (base + 2 >= kst && base + 2 < ket) ? fkey(v2) : kneg;
    keys[base + 3] = (base + 3 >= kst && base + 3 < ket) ? fkey(v3) : kneg;
  }
  __syncthreads();
  if (limit > K){
    u32 prefix = 0, pmask = 0, rem = (u32)K;
    for (int p = 3; p >= 0; p--){
      int sh = p * 8;
      hist[tid] = 0;
      __syncthreads();
      for (int i = tid; i < limit; i += 256){
        u32 u = keys[i];
        if ((u & pmask) == prefix) atomicAdd(&hist[(u >> sh) & 255], 1u);
      }
      __syncthreads();
      ssum[tid] = hist[tid];
      __syncthreads();
      for (int off = 1; off < 256; off <<= 1){
        u32 add = (tid + off < 256) ? ssum[tid + off] : 0u;
        __syncthreads();
        ssum[tid] += add;
        __syncthreads();
      }
      u32 mine = ssum[tid];
      u32 above = (tid == 255) ? 0u : ssum[tid + 1];
      if (mine >= rem && above < rem){ sb = (u32)tid; srem = rem - above; }
      __syncthreads();
      prefix |= (sb << sh);
      pmask |= (255u << sh);
      rem = srem;
      __syncthreads();
    }
    u32 thr = prefix;
    int G = K - (int)rem;
    if (tid == 0){ baseGt = 0; baseTie = 0; }
    __syncthreads();
    int nch = limit >> 8;
    for (int ch = 0; ch < nch; ch++){
      int i = ch * 256 + tid;
      u32 u = keys[i];
      bool gt = (u > thr), tie = (u == thr);
      u64 bg = __ballot(gt), bt = __ballot(tie);
      int lane = tid & 63, w = tid >> 6;
      if (lane == 0){ wtot[w] = (u32)__popcll(bg); wtot[4 + w] = (u32)__popcll(bt); }
      __syncthreads();
      u32 og = baseGt, ot = baseTie;
      for (int ww = 0; ww < w; ww++){ og += wtot[ww]; ot += wtot[4 + ww]; }
      og += (u32)__popcll(bg & ((1ull << lane) - 1ull));
      ot += (u32)__popcll(bt & ((1ull << lane) - 1ull));
      if (gt) selIdx[og] = i;
      else if (tie && ot < rem) selIdx[G + ot] = i;
      __syncthreads();
      if (tid == 0){
        for (int ww = 0; ww < 4; ww++){ baseGt += wtot[ww]; baseTie += wtot[4 + ww]; }
      }
      __syncthreads();
    }
    if (tid < K){
      int si = selIdx[tid];
      u32 u = keys[si];
      skey[tid] = ((u64)(~u) << 32) | (u32)si;   // value desc, idx asc
    } else {
      skey[tid] = ~0ull;
    }
  } else {
    if (tid < K) skey[tid] = ((u64)(~keys[tid]) << 32) | (u32)tid;
    else skey[tid] = ~0ull;
  }
  __syncthreads();
  for (int size = 2; size <= 256; size <<= 1){
    for (int stride = size >> 1; stride > 0; stride >>= 1){
      int p = tid ^ stride;
      if (p > tid){
        bool up = ((tid & size) == 0);
        u64 a = skey[tid], b = skey[p];
        if ((a > b) == up){ skey[tid] = b; skey[p] = a; }
      }
      __syncthreads();
    }
  }
  if (tid < K){
    u64 sk = skey[tid];
    int idx = (int)(u32)(sk & 0xFFFFFFFFu);
    float val = unkey(~(u32)(sk >> 32));
    out[(size_t)t * K + tid] = (float)idx;                      // idx chunk (as float)
    out[(size_t)T * K + (size_t)t * K + tid] = val;             // values chunk
  }
}

extern "C" void kernel_launch(void* const* d_in, const int* in_sizes, int n_in,
                              void* d_out, int out_size, void* d_ws, size_t ws_size,
                              hipStream_t stream){
  const float* hs   = (const float*)d_in[0];
  const float* ql   = (const float*)d_in[1];
  const int*   ks   = (const int*)  d_in[2];
  const int*   ke   = (const int*)  d_in[3];
  const float* cosp = (const float*)d_in[4];
  const float* sinp = (const float*)d_in[5];
  const float* wqb  = (const float*)d_in[6];
  const float* wk   = (const float*)d_in[7];
  const float* kg   = (const float*)d_in[8];
  const float* kb   = (const float*)d_in[9];
  const float* wp   = (const float*)d_in[10];
  const int*   ktp  = (const int*)  d_in[11];

  char* w = (char*)d_ws;
  u16* qlb = (u16*)w;  w += (size_t)2048 * 1536 * 2;   // [0, 6.29MB)
  u16* wqT = (u16*)w;  w += (size_t)4096 * 1536 * 2;   // [6.29, 18.87MB)
  u16* wct = (u16*)w;  w += (size_t)192 * 4096 * 2;
  u16* qb  = (u16*)w;  w += (size_t)2048 * 4096 * 2;
  float* kwp = (float*)w; w += (size_t)8 * 2048 * 192 * 4;
  float* wfin = (float*)w; w += (size_t)2048 * 32 * 4;
  u16* krt = (u16*)w;  w += (size_t)2048 * 128 * 2;
  float* S0 = (float*)w; w += (size_t)2048 * 2048 * 4;
  int* list = (int*)w;  w += 2048 * 4;
  int* qcnt = (int*)w;  w += 8 * 4;
  // S1 aliases qlb+wqT (16.78MB <= 18.87MB): lifetime-disjoint.
  float* S1 = (float*)d_ws;

  hipLaunchKernelGGL(k_init, dim3(1), dim3(256), 0, stream, ke, list, qcnt);
  hipLaunchKernelGGL(k_cvt, dim3(1536), dim3(256), 0, stream, ql, qlb, 393216);
  hipLaunchKernelGGL(k_tcvt, dim3(128, 48), dim3(256), 0, stream, wqb, wqT, 1536, 4096);
  hipLaunchKernelGGL(k_wct, dim3(6, 128), dim3(256), 0, stream, wk, wp, wct);
  hipLaunchKernelGGL(k_gemm_kw, dim3(384), dim3(256), 0, stream, hs, wct, kwp);
  hipLaunchKernelGGL(k_lnrope, dim3(512), dim3(256), 0, stream, kwp, kg, kb, cosp, sinp, krt, wfin);
  hipLaunchKernelGGL(k_gemm_q, dim3(512), dim3(256), 0, stream, qlb, wqT, cosp, sinp, qb);
  hipLaunchKernelGGL(k_scores, dim3(1024), dim3(256), 0, stream, qb, krt, wfin, list, qcnt, S0, S1);
  hipLaunchKernelGGL(k_topk, dim3(2048), dim3(256), 0, stream, S0, S1, ktp, ks, ke, (float*)d_out);
}

// Round 18
// 173.677 us; speedup vs baseline: 1.4846x; 1.0125x over previous
//
#include <hip/hip_runtime.h>
#include <cstdint>

typedef unsigned short u16;
typedef unsigned int   u32;
typedef unsigned long long u64;

typedef short bf16x8 __attribute__((ext_vector_type(8)));
typedef float f32x4  __attribute__((ext_vector_type(4)));
typedef u16   u16x8  __attribute__((ext_vector_type(8)));

__device__ __forceinline__ u16 f2b(float f){
  u32 u = __float_as_uint(f);
  u += 0x7FFFu + ((u >> 16) & 1u);
  return (u16)(u >> 16);
}
__device__ __forceinline__ float b2f(u16 h){ return __uint_as_float(((u32)h) << 16); }
__device__ __forceinline__ u32 fkey(float f){
  u32 u = __float_as_uint(f);
  return u ^ ((u & 0x80000000u) ? 0xFFFFFFFFu : 0x80000000u);
}
__device__ __forceinline__ float unkey(u32 k){
  u32 u = (k & 0x80000000u) ? (k ^ 0x80000000u) : ~k;
  return __uint_as_float(u);
}
__device__ __forceinline__ void gload16(const void* g, void* l){
  __builtin_amdgcn_global_load_lds(
      reinterpret_cast<const __attribute__((address_space(1))) char*>(reinterpret_cast<uintptr_t>(g)),
      reinterpret_cast<__attribute__((address_space(3))) char*>(reinterpret_cast<uintptr_t>(l)),
      16, 0, 0);
}

// ---------------- init: per-t-tile kemax + compacted per-XCD work list ----------------
__global__ __launch_bounds__(256) void k_init(const int* __restrict__ ke, int* __restrict__ list){
  __shared__ int km[64];
  int tid = threadIdx.x;
  if (tid < 64){
    int m = 0;
    for (int j = 0; j < 32; j++) m = max(m, ke[tid * 32 + j]);
    km[tid] = m;
  }
  __syncthreads();
  if (tid < 8){
    int x = tid, n = 0;
    for (int j0 = 0; j0 < 8; j0++){
      int tb = j0 * 8 + x;
      int kmax = km[tb];
      for (int sb = 0; sb < 16; sb++){
        if (sb * 128 < kmax){
          list[n * 8 + x] = tb * 32 + sb * 2 + 0; n++;
          list[n * 8 + x] = tb * 32 + sb * 2 + 1; n++;
        }
      }
    }
    for (; n < 256; n++) list[n * 8 + x] = -1;
  }
}

// ---------------- transpose-convert: out[c][r] = bf16(in[r][c]) ----------------
__global__ __launch_bounds__(256) void k_tcvt(const float* __restrict__ in, u16* __restrict__ out, int R, int C){
  __shared__ float tile[32][33];
  int c0 = blockIdx.x * 32, r0 = blockIdx.y * 32;
  int tx = threadIdx.x & 31, ty = threadIdx.x >> 5;   // ty 0..7
  for (int i = 0; i < 4; i++){
    int r = ty * 4 + i;
    tile[r][tx] = in[(size_t)(r0 + r) * C + c0 + tx];
  }
  __syncthreads();
  for (int i = 0; i < 4; i++){
    int c = ty * 4 + i;
    out[(size_t)(c0 + c) * R + r0 + tx] = f2b(tile[tx][c]);
  }
}

// ---------------- build WC^T: out[c][i], c<128 from wk, 128..159 from w_proj, pad 0 ----------------
__global__ __launch_bounds__(256) void k_wct(const float* __restrict__ wk, const float* __restrict__ wp, u16* __restrict__ out){
  __shared__ float tile[32][33];
  int c0 = blockIdx.x * 32, i0 = blockIdx.y * 32;
  int tx = threadIdx.x & 31, ty = threadIdx.x >> 5;
  for (int j = 0; j < 4; j++){
    int i = i0 + ty * 4 + j;
    int c = c0 + tx;
    float v = 0.f;
    if (c < 128) v = wk[(size_t)i * 128 + c];
    else if (c < 160) v = wp[(size_t)i * 32 + (c - 128)];
    tile[ty * 4 + j][tx] = v;  // tile[i_local][c_local]
  }
  __syncthreads();
  for (int j = 0; j < 4; j++){
    int c = c0 + ty * 4 + j;
    out[(size_t)c * 4096 + i0 + tx] = f2b(tile[tx][ty * 4 + j]);
  }
}

// ---------------- GEMM kw partial: kwp[z][2048][192]; swizzled LDS (rule #21c) ----------------
__global__ __launch_bounds__(256) void k_gemm_kw(const float* __restrict__ A, const u16* __restrict__ B, float* __restrict__ Cp){
  const int Kd = 4096, NC = 192;
  __shared__ float As[128 * 64];   // 32KB, f32 staging; 16B chunk slot ^= row&7 (slots 0..15)
  __shared__ u16 Bs[64 * 64];      // 8KB; slot ^= row&7 (slots 0..7)
  int lin = blockIdx.x;
  int xcd = lin & 7, idx = lin >> 3;
  int nb = idx % 3, pz = idx / 3;
  int p = xcd + 8 * pz;            // 0..127
  int m0 = (p & 15) * 128;
  int kt0 = (p >> 4) * 512;
  int n0 = nb * 64;
  float* C = Cp + (size_t)(p >> 4) * 2048 * NC;
  int tid = threadIdx.x, lane = tid & 63, wid = tid >> 6;
  int wm = wid * 32;
  f32x4 acc[2][4] = {};
  for (int kt = kt0; kt < kt0 + 512; kt += 64){
    for (int c = tid; c < 2048; c += 256){
      int row = c >> 4, slot = (c & 15) ^ (row & 7);
      gload16(A + (size_t)(m0 + row) * Kd + kt + slot * 4, (float*)As + (size_t)c * 4);
    }
    for (int c = tid; c < 512; c += 256){
      int row = c >> 3, slot = (c & 7) ^ (row & 7);
      gload16(B + (size_t)(n0 + row) * Kd + kt + slot * 8, (u16*)Bs + (size_t)c * 8);
    }
    __syncthreads();
    for (int kk = 0; kk < 2; kk++){
      bf16x8 af[2], bfr[4];
      for (int i = 0; i < 2; i++){
        int row = wm + i * 16 + (lane & 15);
        int c0 = kk * 8 + (lane >> 4) * 2;  // 16B-chunk index (of 16)
        f32x4 lo = *(const f32x4*)&As[row * 64 + ((c0)     ^ (row & 7)) * 4];
        f32x4 hi = *(const f32x4*)&As[row * 64 + ((c0 + 1) ^ (row & 7)) * 4];
        bf16x8 t;
        t[0]=(short)f2b(lo[0]); t[1]=(short)f2b(lo[1]); t[2]=(short)f2b(lo[2]); t[3]=(short)f2b(lo[3]);
        t[4]=(short)f2b(hi[0]); t[5]=(short)f2b(hi[1]); t[6]=(short)f2b(hi[2]); t[7]=(short)f2b(hi[3]);
        af[i] = t;
      }
      for (int j = 0; j < 4; j++){
        int row = j * 16 + (lane & 15);
        int slot = (kk * 4 + (lane >> 4)) ^ (row & 7);
        bfr[j] = *(const bf16x8*)&Bs[row * 64 + slot * 8];
      }
      for (int i = 0; i < 2; i++)
        for (int j = 0; j < 4; j++)
          acc[i][j] = __builtin_amdgcn_mfma_f32_16x16x32_bf16(af[i], bfr[j], acc[i][j], 0, 0, 0);
    }
    __syncthreads();
  }
  for (int i = 0; i < 2; i++)
    for (int j = 0; j < 4; j++){
      int row = m0 + wm + i * 16 + ((lane >> 4) * 4);
      int col = n0 + j * 16 + (lane & 15);
      for (int r = 0; r < 4; r++)
        C[(size_t)(row + r) * NC + col] = acc[i][j][r];
    }
}

// ---------------- reduce partials + LayerNorm + RoPE -> krot bf16; also wfin[2048][32] f32 ----------------
__global__ __launch_bounds__(256) void k_lnrope(const float* __restrict__ kwp, const float* __restrict__ gamma,
                                                const float* __restrict__ beta, const float* __restrict__ cosp,
                                                const float* __restrict__ sinp, u16* __restrict__ krot,
                                                float* __restrict__ wfin){
  const size_t ZS = (size_t)2048 * 192;
  int row = blockIdx.x * 4 + (threadIdx.x >> 6);
  int lane = threadIdx.x & 63;
  const float* x = kwp + (size_t)row * 192;
  float2 v = {0.f, 0.f};
  for (int z = 0; z < 8; z++){
    float2 p = *(const float2*)&x[z * ZS + lane * 2];
    v.x += p.x; v.y += p.y;
  }
  float s = v.x + v.y, ss = v.x * v.x + v.y * v.y;
  for (int o = 32; o; o >>= 1){ s += __shfl_xor(s, o); ss += __shfl_xor(ss, o); }
  float mu = s * (1.f / 128.f);
  float var = ss * (1.f / 128.f) - mu * mu;
  float rs = rsqrtf(var + 1e-6f);
  float y0 = (v.x - mu) * rs * gamma[lane * 2]     + beta[lane * 2];
  float y1 = (v.y - mu) * rs * gamma[lane * 2 + 1] + beta[lane * 2 + 1];
  u16* out = krot + (size_t)row * 128;
  if (lane < 32){
    float c = cosp[(size_t)row * 64 + lane], sn = sinp[(size_t)row * 64 + lane];
    out[lane]      = f2b(y0 * c - y1 * sn);
    out[lane + 32] = f2b(y1 * c + y0 * sn);
    float wsum = 0.f;
    for (int z = 0; z < 8; z++) wsum += x[z * ZS + 128 + lane];
    wfin[(size_t)row * 32 + lane] = wsum;
  } else {
    out[lane * 2]     = f2b(y0);
    out[lane * 2 + 1] = f2b(y1);
  }
}

// ---------------- GEMM q + fused ql-cvt (f32 A staging) + fused RoPE epilogue; swizzled LDS ----------------
__global__ __launch_bounds__(256) void k_gemm_q(const float* __restrict__ A, const u16* __restrict__ B,
                                                const float* __restrict__ cosp, const float* __restrict__ sinp,
                                                u16* __restrict__ C){
  const int N = 4096, Kd = 1536;
  __shared__ float As[128 * 64];   // 32KB f32 staging; 16B chunk slot ^= row&7 (slots 0..15)
  __shared__ u16 Bs[128 * 64];     // 16KB; slot ^= row&7 (slots 0..7)
  int linb = blockIdx.x;                   // 512 blocks
  int xcd = linb & 7, loc = linb >> 3;     // 64 per XCD
  int n0 = (xcd * 4 + (loc >> 4)) * 128;   // 4 n-panels per XCD -> B slice L2-resident
  int m0 = (loc & 15) * 128;
  int tid = threadIdx.x, lane = tid & 63, wid = tid >> 6;
  int wm = (wid >> 1) * 64, wn = (wid & 1) * 64;
  f32x4 acc[4][4] = {};
  for (int kt = 0; kt < Kd; kt += 64){
    for (int c = tid; c < 2048; c += 256){
      int row = c >> 4, slot = (c & 15) ^ (row & 7);
      gload16(A + (size_t)(m0 + row) * Kd + kt + slot * 4, (float*)As + (size_t)c * 4);
    }
    for (int c = tid; c < 1024; c += 256){
      int row = c >> 3, slot = (c & 7) ^ (row & 7);
      gload16(B + (size_t)(n0 + row) * Kd + kt + slot * 8, (u16*)Bs + (size_t)c * 8);
    }
    __syncthreads();
    for (int kk = 0; kk < 2; kk++){
      bf16x8 af[4], bfr[4];
      for (int i = 0; i < 4; i++){
        int rowa = wm + i * 16 + (lane & 15);
        int c0 = kk * 8 + (lane >> 4) * 2;  // 16B-chunk index (of 16)
        f32x4 lo = *(const f32x4*)&As[rowa * 64 + ((c0)     ^ (rowa & 7)) * 4];
        f32x4 hi = *(const f32x4*)&As[rowa * 64 + ((c0 + 1) ^ (rowa & 7)) * 4];
        bf16x8 t;
        t[0]=(short)f2b(lo[0]); t[1]=(short)f2b(lo[1]); t[2]=(short)f2b(lo[2]); t[3]=(short)f2b(lo[3]);
        t[4]=(short)f2b(hi[0]); t[5]=(short)f2b(hi[1]); t[6]=(short)f2b(hi[2]); t[7]=(short)f2b(hi[3]);
        af[i] = t;
        int rowb = wn + i * 16 + (lane & 15);
        int sbx = (kk * 4 + (lane >> 4)) ^ (rowb & 7);
        bfr[i] = *(const bf16x8*)&Bs[rowb * 64 + sbx * 8];
      }
      for (int i = 0; i < 4; i++)
        for (int j = 0; j < 4; j++)
          acc[i][j] = __builtin_amdgcn_mfma_f32_16x16x32_bf16(af[i], bfr[j], acc[i][j], 0, 0, 0);
    }
    __syncthreads();
  }
  // fused RoPE: wn==0 waves hold dims 0..63 of each head (n0 = head base, 128-wide)
  if (wn == 0){
    int l = lane & 15;
    int base = lane & 48;
    int sl = base + ((2 * l) & 15);
    for (int i = 0; i < 4; i++){
      int rowb = m0 + wm + i * 16 + ((lane >> 4) * 4);
      f32x4 ne[4];
      for (int j = 0; j < 4; j++){
        int jj = j & 1;
        for (int r = 0; r < 4; r++){
          float eA = __shfl(acc[i][2 * jj][r],     sl);
          float eB = __shfl(acc[i][2 * jj + 1][r], sl);
          float oA = __shfl(acc[i][2 * jj][r],     sl + 1);
          float oB = __shfl(acc[i][2 * jj + 1][r], sl + 1);
          float e = (l >= 8) ? eB : eA;
          float o = (l >= 8) ? oB : oA;
          int row = rowb + r;
          int d = j * 16 + l;
          float c = cosp[(size_t)row * 64 + d];
          float s = sinp[(size_t)row * 64 + d];
          ne[j][r] = (j < 2) ? (e * c - o * s) : (o * c + e * s);
        }
      }
      for (int j = 0; j < 4; j++) acc[i][j] = ne[j];
    }
  }
  for (int i = 0; i < 4; i++)
    for (int j = 0; j < 4; j++){
      int row = m0 + wm + i * 16 + ((lane >> 4) * 4);
      int col = n0 + wn + j * 16 + (lane & 15);
      for (int r = 0; r < 4; r++)
        C[(size_t)(row + r) * N + col] = f2b(acc[i][j][r]);
    }
}

// ---------------- scores v14: static compacted list + swizzled Bs (best measured) ----------------
__global__ __launch_bounds__(256, 4) void k_scores(const u16* __restrict__ q, const u16* __restrict__ krot,
                                                   const float* __restrict__ wfin, const int* __restrict__ list,
                                                   float* __restrict__ S0, float* __restrict__ S1){
  __shared__ u16 Bs[128 * 128];     // krot panel (32KB); 16B slot ^= row&7
  __shared__ float Ws[16][32];      // Ws[h][r] for this head group
  int e = list[blockIdx.x];
  if (e < 0) return;
  int tb = e >> 5, sb = (e >> 1) & 15, hgrp = e & 1;
  int t0 = tb * 32, s0 = sb * 128;
  int tid = threadIdx.x, lane = tid & 63, wid = tid >> 6;
  int wr = wid >> 1, wc = wid & 1;  // wave = 16(t) x 64(s) subtile

  for (int c = tid; c < 2048; c += 256){
    int row = c >> 4, slot = (c & 15) ^ (row & 7);
    gload16(krot + (size_t)(s0 + row) * 128 + slot * 8, (u16*)Bs + (size_t)c * 8);
  }
  for (int i = tid; i < 512; i += 256){
    int h = i >> 5, r = i & 31;
    Ws[h][r] = wfin[(size_t)(t0 + r) * 32 + hgrp * 16 + h];
  }
  __syncthreads();

  // hoist B fragments (head-invariant): 16 x b128, one-time swizzled LDS reads
  bf16x8 bfr[4][4];
  for (int j = 0; j < 4; j++)
    for (int kc = 0; kc < 4; kc++){
      int row = wc * 64 + j * 16 + (lane & 15);
      int slot = (kc * 4 + (lane >> 4)) ^ (row & 7);
      bfr[j][kc] = *(const bf16x8*)&Bs[row * 128 + slot * 8];
    }

  f32x4 acc[4] = {};
  const u16* qbase = q + ((size_t)t0 + wr * 16 + (lane & 15)) * 4096 + (size_t)hgrp * 16 * 128 + (lane >> 4) * 8;
  int rbase = wr * 16 + ((lane >> 4) * 4);
  for (int h = 0; h < 16; h++){
    bf16x8 af[4];
    for (int kc = 0; kc < 4; kc++)
      af[kc] = *(const bf16x8*)&qbase[h * 128 + kc * 32];
    f32x4 ah[4] = {};
    for (int kc = 0; kc < 4; kc++)
      for (int j = 0; j < 4; j++)
        ah[j] = __builtin_amdgcn_mfma_f32_16x16x32_bf16(af[kc], bfr[j][kc], ah[j], 0, 0, 0);
    for (int r = 0; r < 4; r++){
      float wv = Ws[h][rbase + r];
      for (int j = 0; j < 4; j++)
        acc[j][r] += fmaxf(ah[j][r], 0.f) * wv;
    }
  }
  float* Sp = hgrp ? S1 : S0;
  for (int j = 0; j < 4; j++){
    int col = s0 + wc * 64 + j * 16 + (lane & 15);
    for (int r = 0; r < 4; r++)
      Sp[(size_t)(t0 + rbase + r) * 2048 + col] = acc[j][r];
  }
}

// ---------------- per-row top-K: sums partials, applies scale, synthesizes masked keys ----------------
__global__ __launch_bounds__(256) void k_topk(const float* __restrict__ S0, const float* __restrict__ S1,
                                              const int* __restrict__ ktp, const int* __restrict__ ksv,
                                              const int* __restrict__ ke, float* __restrict__ out){
  int t = blockIdx.x;
  int T = gridDim.x;
  const float* r0 = S0 + (size_t)t * 2048;
  const float* r1 = S1 + (size_t)t * 2048;
  __shared__ u32 keys[2048];
  __shared__ u32 hist[256];
  __shared__ u32 ssum[256];
  __shared__ u32 sb, srem;
  __shared__ u32 wtot[8];
  __shared__ int selIdx[256];
  __shared__ u32 baseGt, baseTie;
  __shared__ u64 skey[256];
  int tid = threadIdx.x;
  int K = ktp[0]; if (K > 256) K = 256;
  int ket = ke[t]; if (ket < 0) ket = 0; if (ket > 2048) ket = 2048;
  int kst = ksv[t]; if (kst < 0) kst = 0;
  int limit = (ket + 255) & ~255;
  if (limit < 256) limit = 256;
  if (limit > 2048) limit = 2048;
  const u32 kneg = fkey(-1e30f);
  const float scale = 0.015625f;  // 1/sqrt(D*H) = 1/64
  for (int i4 = tid; i4 < (limit >> 2); i4 += 256){
    int base = i4 * 4;
    float4 a = ((const float4*)r0)[i4];
    float4 b = ((const float4*)r1)[i4];
    float v0 = (a.x + b.x) * scale, v1 = (a.y + b.y) * scale;
    float v2 = (a.z + b.z) * scale, v3 = (a.w + b.w) * scale;
    keys[base + 0] = (base + 0 >= kst && base + 0 < ket) ? fkey(v0) : kneg;
    keys[base + 1] = (base + 1 >= kst && base + 1 < ket) ? fkey(v1) : kneg;
    keys[base + 2] = (base + 2 >= kst && base + 2 < ket) ? fkey(v2) : kneg;
    keys[base + 3] = (base + 3 >= kst && base + 3 < ket) ? fkey(v3) : kneg;
  }
  __syncthreads();
  if (limit > K){
    u32 prefix = 0, pmask = 0, rem = (u32)K;
    for (int p = 3; p >= 0; p--){
      int sh = p * 8;
      hist[tid] = 0;
      __syncthreads();
      for (int i = tid; i < limit; i += 256){
        u32 u = keys[i];
        if ((u & pmask) == prefix) atomicAdd(&hist[(u >> sh) & 255], 1u);
      }
      __syncthreads();
      ssum[tid] = hist[tid];
      __syncthreads();
      for (int off = 1; off < 256; off <<= 1){
        u32 add = (tid + off < 256) ? ssum[tid + off] : 0u;
        __syncthreads();
        ssum[tid] += add;
        __syncthreads();
      }
      u32 mine = ssum[tid];
      u32 above = (tid == 255) ? 0u : ssum[tid + 1];
      if (mine >= rem && above < rem){ sb = (u32)tid; srem = rem - above; }
      __syncthreads();
      prefix |= (sb << sh);
      pmask |= (255u << sh);
      rem = srem;
      __syncthreads();
    }
    u32 thr = prefix;
    int G = K - (int)rem;
    if (tid == 0){ baseGt = 0; baseTie = 0; }
    __syncthreads();
    int nch = limit >> 8;
    for (int ch = 0; ch < nch; ch++){
      int i = ch * 256 + tid;
      u32 u = keys[i];
      bool gt = (u > thr), tie = (u == thr);
      u64 bg = __ballot(gt), bt = __ballot(tie);
      int lane = tid & 63, w = tid >> 6;
      if (lane == 0){ wtot[w] = (u32)__popcll(bg); wtot[4 + w] = (u32)__popcll(bt); }
      __syncthreads();
      u32 og = baseGt, ot = baseTie;
      for (int ww = 0; ww < w; ww++){ og += wtot[ww]; ot += wtot[4 + ww]; }
      og += (u32)__popcll(bg & ((1ull << lane) - 1ull));
      ot += (u32)__popcll(bt & ((1ull << lane) - 1ull));
      if (gt) selIdx[og] = i;
      else if (tie && ot < rem) selIdx[G + ot] = i;
      __syncthreads();
      if (tid == 0){
        for (int ww = 0; ww < 4; ww++){ baseGt += wtot[ww]; baseTie += wtot[4 + ww]; }
      }
      __syncthreads();
    }
    if (tid < K){
      int si = selIdx[tid];
      u32 u = keys[si];
      skey[tid] = ((u64)(~u) << 32) | (u32)si;   // value desc, idx asc
    } else {
      skey[tid] = ~0ull;
    }
  } else {
    if (tid < K) skey[tid] = ((u64)(~keys[tid]) << 32) | (u32)tid;
    else skey[tid] = ~0ull;
  }
  __syncthreads();
  for (int size = 2; size <= 256; size <<= 1){
    for (int stride = size >> 1; stride > 0; stride >>= 1){
      int p = tid ^ stride;
      if (p > tid){
        bool up = ((tid & size) == 0);
        u64 a = skey[tid], b = skey[p];
        if ((a > b) == up){ skey[tid] = b; skey[p] = a; }
      }
      __syncthreads();
    }
  }
  if (tid < K){
    u64 sk = skey[tid];
    int idx = (int)(u32)(sk & 0xFFFFFFFFu);
    float val = unkey(~(u32)(sk >> 32));
    out[(size_t)t * K + tid] = (float)idx;                      // idx chunk (as float)
    out[(size_t)T * K + (size_t)t * K + tid] = val;             // values chunk
  }
}

extern "C" void kernel_launch(void* const* d_in, const int* in_sizes, int n_in,
                              void* d_out, int out_size, void* d_ws, size_t ws_size,
                              hipStream_t stream){
  const float* hs   = (const float*)d_in[0];
  const float* ql   = (const float*)d_in[1];
  const int*   ks   = (const int*)  d_in[2];
  const int*   ke   = (const int*)  d_in[3];
  const float* cosp = (const float*)d_in[4];
  const float* sinp = (const float*)d_in[5];
  const float* wqb  = (const float*)d_in[6];
  const float* wk   = (const float*)d_in[7];
  const float* kg   = (const float*)d_in[8];
  const float* kb   = (const float*)d_in[9];
  const float* wp   = (const float*)d_in[10];
  const int*   ktp  = (const int*)  d_in[11];

  char* w = (char*)d_ws;
  u16* qlb = (u16*)w;  w += (size_t)2048 * 1536 * 2;   // reserved (unused; keeps S1 alias layout)
  u16* wqT = (u16*)w;  w += (size_t)4096 * 1536 * 2;   // [6.29, 18.87MB)
  u16* wct = (u16*)w;  w += (size_t)192 * 4096 * 2;
  u16* qb  = (u16*)w;  w += (size_t)2048 * 4096 * 2;
  float* kwp = (float*)w; w += (size_t)8 * 2048 * 192 * 4;
  float* wfin = (float*)w; w += (size_t)2048 * 32 * 4;
  u16* krt = (u16*)w;  w += (size_t)2048 * 128 * 2;
  float* S0 = (float*)w; w += (size_t)2048 * 2048 * 4;
  int* list = (int*)w;  w += 2048 * 4;
  // S1 aliases qlb+wqT (16.78MB <= 18.87MB): lifetime-disjoint — gemm_q finishes
  // reading wqT before k_scores writes S1; tcvt rewrites it next call.
  float* S1 = (float*)d_ws;
  (void)qlb;

  hipLaunchKernelGGL(k_init, dim3(1), dim3(256), 0, stream, ke, list);
  hipLaunchKernelGGL(k_tcvt, dim3(128, 48), dim3(256), 0, stream, wqb, wqT, 1536, 4096);
  hipLaunchKernelGGL(k_wct, dim3(6, 128), dim3(256), 0, stream, wk, wp, wct);
  hipLaunchKernelGGL(k_gemm_kw, dim3(384), dim3(256), 0, stream, hs, wct, kwp);
  hipLaunchKernelGGL(k_lnrope, dim3(512), dim3(256), 0, stream, kwp, kg, kb, cosp, sinp, krt, wfin);
  hipLaunchKernelGGL(k_gemm_q, dim3(512), dim3(256), 0, stream, ql, wqT, cosp, sinp, qb);
  hipLaunchKernelGGL(k_scores, dim3(2048), dim3(256), 0, stream, qb, krt, wfin, list, S0, S1);
  hipLaunchKernelGGL(k_topk, dim3(2048), dim3(256), 0, stream, S0, S1, ktp, ks, ke, (float*)d_out);
}

// Round 19
// 158.410 us; speedup vs baseline: 1.6277x; 1.0964x over previous
//
#include <hip/hip_runtime.h>
#include <cstdint>

typedef unsigned short u16;
typedef unsigned int   u32;
typedef unsigned long long u64;

typedef short bf16x8 __attribute__((ext_vector_type(8)));
typedef float f32x4  __attribute__((ext_vector_type(4)));
typedef u16   u16x8  __attribute__((ext_vector_type(8)));

__device__ __forceinline__ u16 f2b(float f){
  u32 u = __float_as_uint(f);
  u += 0x7FFFu + ((u >> 16) & 1u);
  return (u16)(u >> 16);
}
__device__ __forceinline__ float b2f(u16 h){ return __uint_as_float(((u32)h) << 16); }
__device__ __forceinline__ u32 fkey(float f){
  u32 u = __float_as_uint(f);
  return u ^ ((u & 0x80000000u) ? 0xFFFFFFFFu : 0x80000000u);
}
__device__ __forceinline__ float unkey(u32 k){
  u32 u = (k & 0x80000000u) ? (k ^ 0x80000000u) : ~k;
  return __uint_as_float(u);
}
__device__ __forceinline__ void gload16(const void* g, void* l){
  __builtin_amdgcn_global_load_lds(
      reinterpret_cast<const __attribute__((address_space(1))) char*>(reinterpret_cast<uintptr_t>(g)),
      reinterpret_cast<__attribute__((address_space(3))) char*>(reinterpret_cast<uintptr_t>(l)),
      16, 0, 0);
}

// ---------------- init: per-t-tile kemax + compacted per-XCD work list ----------------
__global__ __launch_bounds__(256) void k_init(const int* __restrict__ ke, int* __restrict__ list){
  __shared__ int km[64];
  int tid = threadIdx.x;
  if (tid < 64){
    int m = 0;
    for (int j = 0; j < 32; j++) m = max(m, ke[tid * 32 + j]);
    km[tid] = m;
  }
  __syncthreads();
  if (tid < 8){
    int x = tid, n = 0;
    for (int j0 = 0; j0 < 8; j0++){
      int tb = j0 * 8 + x;
      int kmax = km[tb];
      for (int sb = 0; sb < 16; sb++){
        if (sb * 128 < kmax){
          list[n * 8 + x] = tb * 32 + sb * 2 + 0; n++;
          list[n * 8 + x] = tb * 32 + sb * 2 + 1; n++;
        }
      }
    }
    for (; n < 256; n++) list[n * 8 + x] = -1;
  }
}

// ---------------- f32 -> bf16 convert (8 elems/thread) ----------------
__global__ __launch_bounds__(256) void k_cvt(const float* __restrict__ in, u16* __restrict__ out, int n8){
  int i = blockIdx.x * 256 + threadIdx.x;
  if (i >= n8) return;
  const float4* p = (const float4*)in + (size_t)i * 2;
  float4 a = p[0], b = p[1];
  u16x8 v;
  v[0]=f2b(a.x); v[1]=f2b(a.y); v[2]=f2b(a.z); v[3]=f2b(a.w);
  v[4]=f2b(b.x); v[5]=f2b(b.y); v[6]=f2b(b.z); v[7]=f2b(b.w);
  *((u16x8*)out + i) = v;
}

// ---------------- transpose-convert: out[c][r] = bf16(in[r][c]) ----------------
__global__ __launch_bounds__(256) void k_tcvt(const float* __restrict__ in, u16* __restrict__ out, int R, int C){
  __shared__ float tile[32][33];
  int c0 = blockIdx.x * 32, r0 = blockIdx.y * 32;
  int tx = threadIdx.x & 31, ty = threadIdx.x >> 5;   // ty 0..7
  for (int i = 0; i < 4; i++){
    int r = ty * 4 + i;
    tile[r][tx] = in[(size_t)(r0 + r) * C + c0 + tx];
  }
  __syncthreads();
  for (int i = 0; i < 4; i++){
    int c = ty * 4 + i;
    out[(size_t)(c0 + c) * R + r0 + tx] = f2b(tile[tx][c]);
  }
}

// ---------------- build WC^T: out[c][i], c<128 from wk, 128..159 from w_proj, pad 0 ----------------
__global__ __launch_bounds__(256) void k_wct(const float* __restrict__ wk, const float* __restrict__ wp, u16* __restrict__ out){
  __shared__ float tile[32][33];
  int c0 = blockIdx.x * 32, i0 = blockIdx.y * 32;
  int tx = threadIdx.x & 31, ty = threadIdx.x >> 5;
  for (int j = 0; j < 4; j++){
    int i = i0 + ty * 4 + j;
    int c = c0 + tx;
    float v = 0.f;
    if (c < 128) v = wk[(size_t)i * 128 + c];
    else if (c < 160) v = wp[(size_t)i * 32 + (c - 128)];
    tile[ty * 4 + j][tx] = v;  // tile[i_local][c_local]
  }
  __syncthreads();
  for (int j = 0; j < 4; j++){
    int c = c0 + ty * 4 + j;
    out[(size_t)c * 4096 + i0 + tx] = f2b(tile[tx][ty * 4 + j]);
  }
}

// ---------------- GEMM kw partial: kwp[z][2048][192]; swizzled LDS (rule #21c) ----------------
__global__ __launch_bounds__(256) void k_gemm_kw(const float* __restrict__ A, const u16* __restrict__ B, float* __restrict__ Cp){
  const int Kd = 4096, NC = 192;
  __shared__ float As[128 * 64];   // 32KB, f32 staging; 16B chunk slot ^= row&7 (slots 0..15)
  __shared__ u16 Bs[64 * 64];      // 8KB; slot ^= row&7 (slots 0..7)
  int lin = blockIdx.x;
  int xcd = lin & 7, idx = lin >> 3;
  int nb = idx % 3, pz = idx / 3;
  int p = xcd + 8 * pz;            // 0..127
  int m0 = (p & 15) * 128;
  int kt0 = (p >> 4) * 512;
  int n0 = nb * 64;
  float* C = Cp + (size_t)(p >> 4) * 2048 * NC;
  int tid = threadIdx.x, lane = tid & 63, wid = tid >> 6;
  int wm = wid * 32;
  f32x4 acc[2][4] = {};
  for (int kt = kt0; kt < kt0 + 512; kt += 64){
    for (int c = tid; c < 2048; c += 256){
      int row = c >> 4, slot = (c & 15) ^ (row & 7);
      gload16(A + (size_t)(m0 + row) * Kd + kt + slot * 4, (float*)As + (size_t)c * 4);
    }
    for (int c = tid; c < 512; c += 256){
      int row = c >> 3, slot = (c & 7) ^ (row & 7);
      gload16(B + (size_t)(n0 + row) * Kd + kt + slot * 8, (u16*)Bs + (size_t)c * 8);
    }
    __syncthreads();
    for (int kk = 0; kk < 2; kk++){
      bf16x8 af[2], bfr[4];
      for (int i = 0; i < 2; i++){
        int row = wm + i * 16 + (lane & 15);
        int c0 = kk * 8 + (lane >> 4) * 2;  // 16B-chunk index (of 16)
        f32x4 lo = *(const f32x4*)&As[row * 64 + ((c0)     ^ (row & 7)) * 4];
        f32x4 hi = *(const f32x4*)&As[row * 64 + ((c0 + 1) ^ (row & 7)) * 4];
        bf16x8 t;
        t[0]=(short)f2b(lo[0]); t[1]=(short)f2b(lo[1]); t[2]=(short)f2b(lo[2]); t[3]=(short)f2b(lo[3]);
        t[4]=(short)f2b(hi[0]); t[5]=(short)f2b(hi[1]); t[6]=(short)f2b(hi[2]); t[7]=(short)f2b(hi[3]);
        af[i] = t;
      }
      for (int j = 0; j < 4; j++){
        int row = j * 16 + (lane & 15);
        int slot = (kk * 4 + (lane >> 4)) ^ (row & 7);
        bfr[j] = *(const bf16x8*)&Bs[row * 64 + slot * 8];
      }
      for (int i = 0; i < 2; i++)
        for (int j = 0; j < 4; j++)
          acc[i][j] = __builtin_amdgcn_mfma_f32_16x16x32_bf16(af[i], bfr[j], acc[i][j], 0, 0, 0);
    }
    __syncthreads();
  }
  for (int i = 0; i < 2; i++)
    for (int j = 0; j < 4; j++){
      int row = m0 + wm + i * 16 + ((lane >> 4) * 4);
      int col = n0 + j * 16 + (lane & 15);
      for (int r = 0; r < 4; r++)
        C[(size_t)(row + r) * NC + col] = acc[i][j][r];
    }
}

// ---------------- reduce partials + LayerNorm + RoPE -> krot bf16; also wfin[2048][32] f32 ----------------
__global__ __launch_bounds__(256) void k_lnrope(const float* __restrict__ kwp, const float* __restrict__ gamma,
                                                const float* __restrict__ beta, const float* __restrict__ cosp,
                                                const float* __restrict__ sinp, u16* __restrict__ krot,
                                                float* __restrict__ wfin){
  const size_t ZS = (size_t)2048 * 192;
  int row = blockIdx.x * 4 + (threadIdx.x >> 6);
  int lane = threadIdx.x & 63;
  const float* x = kwp + (size_t)row * 192;
  float2 v = {0.f, 0.f};
  for (int z = 0; z < 8; z++){
    float2 p = *(const float2*)&x[z * ZS + lane * 2];
    v.x += p.x; v.y += p.y;
  }
  float s = v.x + v.y, ss = v.x * v.x + v.y * v.y;
  for (int o = 32; o; o >>= 1){ s += __shfl_xor(s, o); ss += __shfl_xor(ss, o); }
  float mu = s * (1.f / 128.f);
  float var = ss * (1.f / 128.f) - mu * mu;
  float rs = rsqrtf(var + 1e-6f);
  float y0 = (v.x - mu) * rs * gamma[lane * 2]     + beta[lane * 2];
  float y1 = (v.y - mu) * rs * gamma[lane * 2 + 1] + beta[lane * 2 + 1];
  u16* out = krot + (size_t)row * 128;
  if (lane < 32){
    float c = cosp[(size_t)row * 64 + lane], sn = sinp[(size_t)row * 64 + lane];
    out[lane]      = f2b(y0 * c - y1 * sn);
    out[lane + 32] = f2b(y1 * c + y0 * sn);
    float wsum = 0.f;
    for (int z = 0; z < 8; z++) wsum += x[z * ZS + 128 + lane];
    wfin[(size_t)row * 32 + lane] = wsum;
  } else {
    out[lane * 2]     = f2b(y0);
    out[lane * 2 + 1] = f2b(y1);
  }
}

// ---------------- GEMM q + fused RoPE epilogue; swizzled LDS (rule #21c) ----------------
__global__ __launch_bounds__(256) void k_gemm_q(const u16* __restrict__ A, const u16* __restrict__ B,
                                                const float* __restrict__ cosp, const float* __restrict__ sinp,
                                                u16* __restrict__ C){
  const int N = 4096, Kd = 1536;
  __shared__ u16 As[128 * 64];
  __shared__ u16 Bs[128 * 64];
  int linb = blockIdx.x;                   // 512 blocks
  int xcd = linb & 7, loc = linb >> 3;     // 64 per XCD
  int n0 = (xcd * 4 + (loc >> 4)) * 128;   // 4 n-panels per XCD -> B slice L2-resident
  int m0 = (loc & 15) * 128;
  int tid = threadIdx.x, lane = tid & 63, wid = tid >> 6;
  int wm = (wid >> 1) * 64, wn = (wid & 1) * 64;
  f32x4 acc[4][4] = {};
  for (int kt = 0; kt < Kd; kt += 64){
    for (int c = tid; c < 1024; c += 256){
      int row = c >> 3, slot = (c & 7) ^ (row & 7);
      gload16(A + (size_t)(m0 + row) * Kd + kt + slot * 8, (u16*)As + (size_t)c * 8);
      gload16(B + (size_t)(n0 + row) * Kd + kt + slot * 8, (u16*)Bs + (size_t)c * 8);
    }
    __syncthreads();
    for (int kk = 0; kk < 2; kk++){
      bf16x8 af[4], bfr[4];
      for (int i = 0; i < 4; i++){
        int rowa = wm + i * 16 + (lane & 15);
        int rowb = wn + i * 16 + (lane & 15);
        int sa = (kk * 4 + (lane >> 4)) ^ (rowa & 7);
        int sbx = (kk * 4 + (lane >> 4)) ^ (rowb & 7);
        af[i]  = *(const bf16x8*)&As[rowa * 64 + sa * 8];
        bfr[i] = *(const bf16x8*)&Bs[rowb * 64 + sbx * 8];
      }
      for (int i = 0; i < 4; i++)
        for (int j = 0; j < 4; j++)
          acc[i][j] = __builtin_amdgcn_mfma_f32_16x16x32_bf16(af[i], bfr[j], acc[i][j], 0, 0, 0);
    }
    __syncthreads();
  }
  // fused RoPE: wn==0 waves hold dims 0..63 of each head (n0 = head base, 128-wide)
  if (wn == 0){
    int l = lane & 15;
    int base = lane & 48;
    int sl = base + ((2 * l) & 15);
    for (int i = 0; i < 4; i++){
      int rowb = m0 + wm + i * 16 + ((lane >> 4) * 4);
      f32x4 ne[4];
      for (int j = 0; j < 4; j++){
        int jj = j & 1;
        for (int r = 0; r < 4; r++){
          float eA = __shfl(acc[i][2 * jj][r],     sl);
          float eB = __shfl(acc[i][2 * jj + 1][r], sl);
          float oA = __shfl(acc[i][2 * jj][r],     sl + 1);
          float oB = __shfl(acc[i][2 * jj + 1][r], sl + 1);
          float e = (l >= 8) ? eB : eA;
          float o = (l >= 8) ? oB : oA;
          int row = rowb + r;
          int d = j * 16 + l;
          float c = cosp[(size_t)row * 64 + d];
          float s = sinp[(size_t)row * 64 + d];
          ne[j][r] = (j < 2) ? (e * c - o * s) : (o * c + e * s);
        }
      }
      for (int j = 0; j < 4; j++) acc[i][j] = ne[j];
    }
  }
  for (int i = 0; i < 4; i++)
    for (int j = 0; j < 4; j++){
      int row = m0 + wm + i * 16 + ((lane >> 4) * 4);
      int col = n0 + wn + j * 16 + (lane & 15);
      for (int r = 0; r < 4; r++)
        C[(size_t)(row + r) * N + col] = f2b(acc[i][j][r]);
    }
}

// ---------------- scores v14: static compacted list + swizzled Bs (best measured) ----------------
__global__ __launch_bounds__(256, 4) void k_scores(const u16* __restrict__ q, const u16* __restrict__ krot,
                                                   const float* __restrict__ wfin, const int* __restrict__ list,
                                                   float* __restrict__ S0, float* __restrict__ S1){
  __shared__ u16 Bs[128 * 128];     // krot panel (32KB); 16B slot ^= row&7
  __shared__ float Ws[16][32];      // Ws[h][r] for this head group
  int e = list[blockIdx.x];
  if (e < 0) return;
  int tb = e >> 5, sb = (e >> 1) & 15, hgrp = e & 1;
  int t0 = tb * 32, s0 = sb * 128;
  int tid = threadIdx.x, lane = tid & 63, wid = tid >> 6;
  int wr = wid >> 1, wc = wid & 1;  // wave = 16(t) x 64(s) subtile

  for (int c = tid; c < 2048; c += 256){
    int row = c >> 4, slot = (c & 15) ^ (row & 7);
    gload16(krot + (size_t)(s0 + row) * 128 + slot * 8, (u16*)Bs + (size_t)c * 8);
  }
  for (int i = tid; i < 512; i += 256){
    int h = i >> 5, r = i & 31;
    Ws[h][r] = wfin[(size_t)(t0 + r) * 32 + hgrp * 16 + h];
  }
  __syncthreads();

  // hoist B fragments (head-invariant): 16 x b128, one-time swizzled LDS reads
  bf16x8 bfr[4][4];
  for (int j = 0; j < 4; j++)
    for (int kc = 0; kc < 4; kc++){
      int row = wc * 64 + j * 16 + (lane & 15);
      int slot = (kc * 4 + (lane >> 4)) ^ (row & 7);
      bfr[j][kc] = *(const bf16x8*)&Bs[row * 128 + slot * 8];
    }

  f32x4 acc[4] = {};
  const u16* qbase = q + ((size_t)t0 + wr * 16 + (lane & 15)) * 4096 + (size_t)hgrp * 16 * 128 + (lane >> 4) * 8;
  int rbase = wr * 16 + ((lane >> 4) * 4);
  for (int h = 0; h < 16; h++){
    bf16x8 af[4];
    for (int kc = 0; kc < 4; kc++)
      af[kc] = *(const bf16x8*)&qbase[h * 128 + kc * 32];
    f32x4 ah[4] = {};
    for (int kc = 0; kc < 4; kc++)
      for (int j = 0; j < 4; j++)
        ah[j] = __builtin_amdgcn_mfma_f32_16x16x32_bf16(af[kc], bfr[j][kc], ah[j], 0, 0, 0);
    for (int r = 0; r < 4; r++){
      float wv = Ws[h][rbase + r];
      for (int j = 0; j < 4; j++)
        acc[j][r] += fmaxf(ah[j][r], 0.f) * wv;
    }
  }
  float* Sp = hgrp ? S1 : S0;
  for (int j = 0; j < 4; j++){
    int col = s0 + wc * 64 + j * 16 + (lane & 15);
    for (int r = 0; r < 4; r++)
      Sp[(size_t)(t0 + rbase + r) * 2048 + col] = acc[j][r];
  }
}

// ---------------- per-row top-K: sums partials, applies scale, synthesizes masked keys ----------------
__global__ __launch_bounds__(256) void k_topk(const float* __restrict__ S0, const float* __restrict__ S1,
                                              const int* __restrict__ ktp, const int* __restrict__ ksv,
                                              const int* __restrict__ ke, float* __restrict__ out){
  int t = blockIdx.x;
  int T = gridDim.x;
  const float* r0 = S0 + (size_t)t * 2048;
  const float* r1 = S1 + (size_t)t * 2048;
  __shared__ u32 keys[2048];
  __shared__ u32 hist[256];
  __shared__ u32 ssum[256];
  __shared__ u32 sb, srem;
  __shared__ u32 wtot[8];
  __shared__ int selIdx[256];
  __shared__ u32 baseGt, baseTie;
  __shared__ u64 skey[256];
  int tid = threadIdx.x;
  int K = ktp[0]; if (K > 256) K = 256;
  int ket = ke[t]; if (ket < 0) ket = 0; if (ket > 2048) ket = 2048;
  int kst = ksv[t]; if (kst < 0) kst = 0;
  int limit = (ket + 255) & ~255;
  if (limit < 256) limit = 256;
  if (limit > 2048) limit = 2048;
  const u32 kneg = fkey(-1e30f);
  const float scale = 0.015625f;  // 1/sqrt(D*H) = 1/64
  for (int i4 = tid; i4 < (limit >> 2); i4 += 256){
    int base = i4 * 4;
    float4 a = ((const float4*)r0)[i4];
    float4 b = ((const float4*)r1)[i4];
    float v0 = (a.x + b.x) * scale, v1 = (a.y + b.y) * scale;
    float v2 = (a.z + b.z) * scale, v3 = (a.w + b.w) * scale;
    keys[base + 0] = (base + 0 >= kst && base + 0 < ket) ? fkey(v0) : kneg;
    keys[base + 1] = (base + 1 >= kst && base + 1 < ket) ? fkey(v1) : kneg;
    keys[base + 2] = (base + 2 >= kst && base + 2 < ket) ? fkey(v2) : kneg;
    keys[base + 3] = (base + 3 >= kst && base + 3 < ket) ? fkey(v3) : kneg;
  }
  __syncthreads();
  if (limit > K){
    u32 prefix = 0, pmask = 0, rem = (u32)K;
    for (int p = 3; p >= 0; p--){
      int sh = p * 8;
      hist[tid] = 0;
      __syncthreads();
      for (int i = tid; i < limit; i += 256){
        u32 u = keys[i];
        if ((u & pmask) == prefix) atomicAdd(&hist[(u >> sh) & 255], 1u);
      }
      __syncthreads();
      ssum[tid] = hist[tid];
      __syncthreads();
      for (int off = 1; off < 256; off <<= 1){
        u32 add = (tid + off < 256) ? ssum[tid + off] : 0u;
        __syncthreads();
        ssum[tid] += add;
        __syncthreads();
      }
      u32 mine = ssum[tid];
      u32 above = (tid == 255) ? 0u : ssum[tid + 1];
      if (mine >= rem && above < rem){ sb = (u32)tid; srem = rem - above; }
      __syncthreads();
      prefix |= (sb << sh);
      pmask |= (255u << sh);
      rem = srem;
      __syncthreads();
    }
    u32 thr = prefix;
    int G = K - (int)rem;
    if (tid == 0){ baseGt = 0; baseTie = 0; }
    __syncthreads();
    int nch = limit >> 8;
    for (int ch = 0; ch < nch; ch++){
      int i = ch * 256 + tid;
      u32 u = keys[i];
      bool gt = (u > thr), tie = (u == thr);
      u64 bg = __ballot(gt), bt = __ballot(tie);
      int lane = tid & 63, w = tid >> 6;
      if (lane == 0){ wtot[w] = (u32)__popcll(bg); wtot[4 + w] = (u32)__popcll(bt); }
      __syncthreads();
      u32 og = baseGt, ot = baseTie;
      for (int ww = 0; ww < w; ww++){ og += wtot[ww]; ot += wtot[4 + ww]; }
      og += (u32)__popcll(bg & ((1ull << lane) - 1ull));
      ot += (u32)__popcll(bt & ((1ull << lane) - 1ull));
      if (gt) selIdx[og] = i;
      else if (tie && ot < rem) selIdx[G + ot] = i;
      __syncthreads();
      if (tid == 0){
        for (int ww = 0; ww < 4; ww++){ baseGt += wtot[ww]; baseTie += wtot[4 + ww]; }
      }
      __syncthreads();
    }
    if (tid < K){
      int si = selIdx[tid];
      u32 u = keys[si];
      skey[tid] = ((u64)(~u) << 32) | (u32)si;   // value desc, idx asc
    } else {
      skey[tid] = ~0ull;
    }
  } else {
    if (tid < K) skey[tid] = ((u64)(~keys[tid]) << 32) | (u32)tid;
    else skey[tid] = ~0ull;
  }
  __syncthreads();
  for (int size = 2; size <= 256; size <<= 1){
    for (int stride = size >> 1; stride > 0; stride >>= 1){
      int p = tid ^ stride;
      if (p > tid){
        bool up = ((tid & size) == 0);
        u64 a = skey[tid], b = skey[p];
        if ((a > b) == up){ skey[tid] = b; skey[p] = a; }
      }
      __syncthreads();
    }
  }
  if (tid < K){
    u64 sk = skey[tid];
    int idx = (int)(u32)(sk & 0xFFFFFFFFu);
    float val = unkey(~(u32)(sk >> 32));
    out[(size_t)t * K + tid] = (float)idx;                      // idx chunk (as float)
    out[(size_t)T * K + (size_t)t * K + tid] = val;             // values chunk
  }
}

extern "C" void kernel_launch(void* const* d_in, const int* in_sizes, int n_in,
                              void* d_out, int out_size, void* d_ws, size_t ws_size,
                              hipStream_t stream){
  const float* hs   = (const float*)d_in[0];
  const float* ql   = (const float*)d_in[1];
  const int*   ks   = (const int*)  d_in[2];
  const int*   ke   = (const int*)  d_in[3];
  const float* cosp = (const float*)d_in[4];
  const float* sinp = (const float*)d_in[5];
  const float* wqb  = (const float*)d_in[6];
  const float* wk   = (const float*)d_in[7];
  const float* kg   = (const float*)d_in[8];
  const float* kb   = (const float*)d_in[9];
  const float* wp   = (const float*)d_in[10];
  const int*   ktp  = (const int*)  d_in[11];

  char* w = (char*)d_ws;
  u16* qlb = (u16*)w;  w += (size_t)2048 * 1536 * 2;   // [0, 6.29MB)
  u16* wqT = (u16*)w;  w += (size_t)4096 * 1536 * 2;   // [6.29, 18.87MB)
  u16* wct = (u16*)w;  w += (size_t)192 * 4096 * 2;
  u16* qb  = (u16*)w;  w += (size_t)2048 * 4096 * 2;
  float* kwp = (float*)w; w += (size_t)8 * 2048 * 192 * 4;
  float* wfin = (float*)w; w += (size_t)2048 * 32 * 4;
  u16* krt = (u16*)w;  w += (size_t)2048 * 128 * 2;
  float* S0 = (float*)w; w += (size_t)2048 * 2048 * 4;
  int* list = (int*)w;  w += 2048 * 4;
  // S1 aliases qlb+wqT (16.78MB <= 18.87MB): lifetime-disjoint — gemm_q finishes
  // reading qlb/wqT before k_scores writes S1; cvt/tcvt rewrite them next call.
  float* S1 = (float*)d_ws;

  hipLaunchKernelGGL(k_init, dim3(1), dim3(256), 0, stream, ke, list);
  hipLaunchKernelGGL(k_cvt, dim3(1536), dim3(256), 0, stream, ql, qlb, 393216);
  hipLaunchKernelGGL(k_tcvt, dim3(128, 48), dim3(256), 0, stream, wqb, wqT, 1536, 4096);
  hipLaunchKernelGGL(k_wct, dim3(6, 128), dim3(256), 0, stream, wk, wp, wct);
  hipLaunchKernelGGL(k_gemm_kw, dim3(384), dim3(256), 0, stream, hs, wct, kwp);
  hipLaunchKernelGGL(k_lnrope, dim3(512), dim3(256), 0, stream, kwp, kg, kb, cosp, sinp, krt, wfin);
  hipLaunchKernelGGL(k_gemm_q, dim3(512), dim3(256), 0, stream, qlb, wqT, cosp, sinp, qb);
  hipLaunchKernelGGL(k_scores, dim3(2048), dim3(256), 0, stream, qb, krt, wfin, list, S0, S1);
  hipLaunchKernelGGL(k_topk, dim3(2048), dim3(256), 0, stream, S0, S1, ktp, ks, ke, (float*)d_out);
}

// Round 20
// 154.725 us; speedup vs baseline: 1.6665x; 1.0238x over previous
//
#include <hip/hip_runtime.h>
#include <cstdint>

typedef unsigned short u16;
typedef unsigned int   u32;
typedef unsigned long long u64;

typedef short bf16x8 __attribute__((ext_vector_type(8)));
typedef float f32x4  __attribute__((ext_vector_type(4)));
typedef u16   u16x8  __attribute__((ext_vector_type(8)));

__device__ __forceinline__ u16 f2b(float f){
  u32 u = __float_as_uint(f);
  u += 0x7FFFu + ((u >> 16) & 1u);
  return (u16)(u >> 16);
}
__device__ __forceinline__ float b2f(u16 h){ return __uint_as_float(((u32)h) << 16); }
__device__ __forceinline__ u32 fkey(float f){
  u32 u = __float_as_uint(f);
  return u ^ ((u & 0x80000000u) ? 0xFFFFFFFFu : 0x80000000u);
}
__device__ __forceinline__ float unkey(u32 k){
  u32 u = (k & 0x80000000u) ? (k ^ 0x80000000u) : ~k;
  return __uint_as_float(u);
}
__device__ __forceinline__ void gload16(const void* g, void* l){
  __builtin_amdgcn_global_load_lds(
      reinterpret_cast<const __attribute__((address_space(1))) char*>(reinterpret_cast<uintptr_t>(g)),
      reinterpret_cast<__attribute__((address_space(3))) char*>(reinterpret_cast<uintptr_t>(l)),
      16, 0, 0);
}

// ---------------- init: per-t-tile kemax + compacted per-XCD work list ----------------
__global__ __launch_bounds__(256) void k_init(const int* __restrict__ ke, int* __restrict__ list){
  __shared__ int km[64];
  int tid = threadIdx.x;
  if (tid < 64){
    int m = 0;
    for (int j = 0; j < 32; j++) m = max(m, ke[tid * 32 + j]);
    km[tid] = m;
  }
  __syncthreads();
  if (tid < 8){
    int x = tid, n = 0;
    for (int j0 = 0; j0 < 8; j0++){
      int tb = j0 * 8 + x;
      int kmax = km[tb];
      for (int sb = 0; sb < 16; sb++){
        if (sb * 128 < kmax){
          list[n * 8 + x] = tb * 32 + sb * 2 + 0; n++;
          list[n * 8 + x] = tb * 32 + sb * 2 + 1; n++;
        }
      }
    }
    for (; n < 256; n++) list[n * 8 + x] = -1;
  }
}

// ---------------- f32 -> bf16 convert (8 elems/thread) ----------------
__global__ __launch_bounds__(256) void k_cvt(const float* __restrict__ in, u16* __restrict__ out, int n8){
  int i = blockIdx.x * 256 + threadIdx.x;
  if (i >= n8) return;
  const float4* p = (const float4*)in + (size_t)i * 2;
  float4 a = p[0], b = p[1];
  u16x8 v;
  v[0]=f2b(a.x); v[1]=f2b(a.y); v[2]=f2b(a.z); v[3]=f2b(a.w);
  v[4]=f2b(b.x); v[5]=f2b(b.y); v[6]=f2b(b.z); v[7]=f2b(b.w);
  *((u16x8*)out + i) = v;
}

// ---------------- transpose-convert: out[c][r] = bf16(in[r][c]) ----------------
__global__ __launch_bounds__(256) void k_tcvt(const float* __restrict__ in, u16* __restrict__ out, int R, int C){
  __shared__ float tile[32][33];
  int c0 = blockIdx.x * 32, r0 = blockIdx.y * 32;
  int tx = threadIdx.x & 31, ty = threadIdx.x >> 5;   // ty 0..7
  for (int i = 0; i < 4; i++){
    int r = ty * 4 + i;
    tile[r][tx] = in[(size_t)(r0 + r) * C + c0 + tx];
  }
  __syncthreads();
  for (int i = 0; i < 4; i++){
    int c = ty * 4 + i;
    out[(size_t)(c0 + c) * R + r0 + tx] = f2b(tile[tx][c]);
  }
}

// ---------------- build WC^T: out[c][i], c<128 from wk, 128..159 from w_proj, pad 0 ----------------
__global__ __launch_bounds__(256) void k_wct(const float* __restrict__ wk, const float* __restrict__ wp, u16* __restrict__ out){
  __shared__ float tile[32][33];
  int c0 = blockIdx.x * 32, i0 = blockIdx.y * 32;
  int tx = threadIdx.x & 31, ty = threadIdx.x >> 5;
  for (int j = 0; j < 4; j++){
    int i = i0 + ty * 4 + j;
    int c = c0 + tx;
    float v = 0.f;
    if (c < 128) v = wk[(size_t)i * 128 + c];
    else if (c < 160) v = wp[(size_t)i * 32 + (c - 128)];
    tile[ty * 4 + j][tx] = v;  // tile[i_local][c_local]
  }
  __syncthreads();
  for (int j = 0; j < 4; j++){
    int c = c0 + ty * 4 + j;
    out[(size_t)c * 4096 + i0 + tx] = f2b(tile[tx][ty * 4 + j]);
  }
}

// ---------------- fused GEMMs: blocks 0..511 = gemm_q (+RoPE); blocks 512..895 = gemm_kw ----------------
__global__ __launch_bounds__(256) void k_gemm_fused(const u16* __restrict__ Aq, const u16* __restrict__ Bq,
                                                    const float* __restrict__ cosp, const float* __restrict__ sinp,
                                                    u16* __restrict__ Cq,
                                                    const float* __restrict__ Akw, const u16* __restrict__ Bkw,
                                                    float* __restrict__ Cp){
  __shared__ char smem[40960];     // union: q = 16K+16K; kw = 32K+8K
  int tid = threadIdx.x, lane = tid & 63, wid = tid >> 6;
  if (blockIdx.x < 512){
    // ---- gemm_q body (R14-proven) ----
    const int N = 4096, Kd = 1536;
    u16* As = (u16*)smem;
    u16* Bs = (u16*)(smem + 16384);
    int linb = blockIdx.x;
    int xcd = linb & 7, loc = linb >> 3;
    int n0 = (xcd * 4 + (loc >> 4)) * 128;
    int m0 = (loc & 15) * 128;
    int wm = (wid >> 1) * 64, wn = (wid & 1) * 64;
    f32x4 acc[4][4] = {};
    for (int kt = 0; kt < Kd; kt += 64){
      for (int c = tid; c < 1024; c += 256){
        int row = c >> 3, slot = (c & 7) ^ (row & 7);
        gload16(Aq + (size_t)(m0 + row) * Kd + kt + slot * 8, As + (size_t)c * 8);
        gload16(Bq + (size_t)(n0 + row) * Kd + kt + slot * 8, Bs + (size_t)c * 8);
      }
      __syncthreads();
      for (int kk = 0; kk < 2; kk++){
        bf16x8 af[4], bfr[4];
        for (int i = 0; i < 4; i++){
          int rowa = wm + i * 16 + (lane & 15);
          int rowb = wn + i * 16 + (lane & 15);
          int sa = (kk * 4 + (lane >> 4)) ^ (rowa & 7);
          int sbx = (kk * 4 + (lane >> 4)) ^ (rowb & 7);
          af[i]  = *(const bf16x8*)&As[rowa * 64 + sa * 8];
          bfr[i] = *(const bf16x8*)&Bs[rowb * 64 + sbx * 8];
        }
        for (int i = 0; i < 4; i++)
          for (int j = 0; j < 4; j++)
            acc[i][j] = __builtin_amdgcn_mfma_f32_16x16x32_bf16(af[i], bfr[j], acc[i][j], 0, 0, 0);
      }
      __syncthreads();
    }
    if (wn == 0){
      int l = lane & 15;
      int base = lane & 48;
      int sl = base + ((2 * l) & 15);
      for (int i = 0; i < 4; i++){
        int rowb = m0 + wm + i * 16 + ((lane >> 4) * 4);
        f32x4 ne[4];
        for (int j = 0; j < 4; j++){
          int jj = j & 1;
          for (int r = 0; r < 4; r++){
            float eA = __shfl(acc[i][2 * jj][r],     sl);
            float eB = __shfl(acc[i][2 * jj + 1][r], sl);
            float oA = __shfl(acc[i][2 * jj][r],     sl + 1);
            float oB = __shfl(acc[i][2 * jj + 1][r], sl + 1);
            float e = (l >= 8) ? eB : eA;
            float o = (l >= 8) ? oB : oA;
            int row = rowb + r;
            int d = j * 16 + l;
            float c = cosp[(size_t)row * 64 + d];
            float s = sinp[(size_t)row * 64 + d];
            ne[j][r] = (j < 2) ? (e * c - o * s) : (o * c + e * s);
          }
        }
        for (int j = 0; j < 4; j++) acc[i][j] = ne[j];
      }
    }
    for (int i = 0; i < 4; i++)
      for (int j = 0; j < 4; j++){
        int row = m0 + wm + i * 16 + ((lane >> 4) * 4);
        int col = n0 + wn + j * 16 + (lane & 15);
        for (int r = 0; r < 4; r++)
          Cq[(size_t)(row + r) * N + col] = f2b(acc[i][j][r]);
      }
  } else {
    // ---- gemm_kw body (R14-proven); lin = blockIdx.x - 512 (512 % 8 == 0 keeps XCD mapping) ----
    const int Kd = 4096, NC = 192;
    float* As = (float*)smem;
    u16* Bs = (u16*)(smem + 32768);
    int lin = blockIdx.x - 512;
    int xcd = lin & 7, idx = lin >> 3;
    int nb = idx % 3, pz = idx / 3;
    int p = xcd + 8 * pz;
    int m0 = (p & 15) * 128;
    int kt0 = (p >> 4) * 512;
    int n0 = nb * 64;
    float* C = Cp + (size_t)(p >> 4) * 2048 * NC;
    int wm = wid * 32;
    f32x4 acc[2][4] = {};
    for (int kt = kt0; kt < kt0 + 512; kt += 64){
      for (int c = tid; c < 2048; c += 256){
        int row = c >> 4, slot = (c & 15) ^ (row & 7);
        gload16(Akw + (size_t)(m0 + row) * Kd + kt + slot * 4, As + (size_t)c * 4);
      }
      for (int c = tid; c < 512; c += 256){
        int row = c >> 3, slot = (c & 7) ^ (row & 7);
        gload16(Bkw + (size_t)(n0 + row) * Kd + kt + slot * 8, Bs + (size_t)c * 8);
      }
      __syncthreads();
      for (int kk = 0; kk < 2; kk++){
        bf16x8 af[2], bfr[4];
        for (int i = 0; i < 2; i++){
          int row = wm + i * 16 + (lane & 15);
          int c0 = kk * 8 + (lane >> 4) * 2;
          f32x4 lo = *(const f32x4*)&As[row * 64 + ((c0)     ^ (row & 7)) * 4];
          f32x4 hi = *(const f32x4*)&As[row * 64 + ((c0 + 1) ^ (row & 7)) * 4];
          bf16x8 t;
          t[0]=(short)f2b(lo[0]); t[1]=(short)f2b(lo[1]); t[2]=(short)f2b(lo[2]); t[3]=(short)f2b(lo[3]);
          t[4]=(short)f2b(hi[0]); t[5]=(short)f2b(hi[1]); t[6]=(short)f2b(hi[2]); t[7]=(short)f2b(hi[3]);
          af[i] = t;
        }
        for (int j = 0; j < 4; j++){
          int row = j * 16 + (lane & 15);
          int slot = (kk * 4 + (lane >> 4)) ^ (row & 7);
          bfr[j] = *(const bf16x8*)&Bs[row * 64 + slot * 8];
        }
        for (int i = 0; i < 2; i++)
          for (int j = 0; j < 4; j++)
            acc[i][j] = __builtin_amdgcn_mfma_f32_16x16x32_bf16(af[i], bfr[j], acc[i][j], 0, 0, 0);
      }
      __syncthreads();
    }
    for (int i = 0; i < 2; i++)
      for (int j = 0; j < 4; j++){
        int row = m0 + wm + i * 16 + ((lane >> 4) * 4);
        int col = n0 + j * 16 + (lane & 15);
        for (int r = 0; r < 4; r++)
          C[(size_t)(row + r) * NC + col] = acc[i][j][r];
      }
  }
}

// ---------------- reduce partials + LayerNorm + RoPE -> krot bf16; also wfin[2048][32] f32 ----------------
__global__ __launch_bounds__(256) void k_lnrope(const float* __restrict__ kwp, const float* __restrict__ gamma,
                                                const float* __restrict__ beta, const float* __restrict__ cosp,
                                                const float* __restrict__ sinp, u16* __restrict__ krot,
                                                float* __restrict__ wfin){
  const size_t ZS = (size_t)2048 * 192;
  int row = blockIdx.x * 4 + (threadIdx.x >> 6);
  int lane = threadIdx.x & 63;
  const float* x = kwp + (size_t)row * 192;
  float2 v = {0.f, 0.f};
  for (int z = 0; z < 8; z++){
    float2 p = *(const float2*)&x[z * ZS + lane * 2];
    v.x += p.x; v.y += p.y;
  }
  float s = v.x + v.y, ss = v.x * v.x + v.y * v.y;
  for (int o = 32; o; o >>= 1){ s += __shfl_xor(s, o); ss += __shfl_xor(ss, o); }
  float mu = s * (1.f / 128.f);
  float var = ss * (1.f / 128.f) - mu * mu;
  float rs = rsqrtf(var + 1e-6f);
  float y0 = (v.x - mu) * rs * gamma[lane * 2]     + beta[lane * 2];
  float y1 = (v.y - mu) * rs * gamma[lane * 2 + 1] + beta[lane * 2 + 1];
  u16* out = krot + (size_t)row * 128;
  if (lane < 32){
    float c = cosp[(size_t)row * 64 + lane], sn = sinp[(size_t)row * 64 + lane];
    out[lane]      = f2b(y0 * c - y1 * sn);
    out[lane + 32] = f2b(y1 * c + y0 * sn);
    float wsum = 0.f;
    for (int z = 0; z < 8; z++) wsum += x[z * ZS + 128 + lane];
    wfin[(size_t)row * 32 + lane] = wsum;
  } else {
    out[lane * 2]     = f2b(y0);
    out[lane * 2 + 1] = f2b(y1);
  }
}

// ---------------- scores v14: static compacted list + swizzled Bs (best measured) ----------------
__global__ __launch_bounds__(256, 4) void k_scores(const u16* __restrict__ q, const u16* __restrict__ krot,
                                                   const float* __restrict__ wfin, const int* __restrict__ list,
                                                   float* __restrict__ S0, float* __restrict__ S1){
  __shared__ u16 Bs[128 * 128];     // krot panel (32KB); 16B slot ^= row&7
  __shared__ float Ws[16][32];      // Ws[h][r] for this head group
  int e = list[blockIdx.x];
  if (e < 0) return;
  int tb = e >> 5, sb = (e >> 1) & 15, hgrp = e & 1;
  int t0 = tb * 32, s0 = sb * 128;
  int tid = threadIdx.x, lane = tid & 63, wid = tid >> 6;
  int wr = wid >> 1, wc = wid & 1;  // wave = 16(t) x 64(s) subtile

  for (int c = tid; c < 2048; c += 256){
    int row = c >> 4, slot = (c & 15) ^ (row & 7);
    gload16(krot + (size_t)(s0 + row) * 128 + slot * 8, (u16*)Bs + (size_t)c * 8);
  }
  for (int i = tid; i < 512; i += 256){
    int h = i >> 5, r = i & 31;
    Ws[h][r] = wfin[(size_t)(t0 + r) * 32 + hgrp * 16 + h];
  }
  __syncthreads();

  // hoist B fragments (head-invariant): 16 x b128, one-time swizzled LDS reads
  bf16x8 bfr[4][4];
  for (int j = 0; j < 4; j++)
    for (int kc = 0; kc < 4; kc++){
      int row = wc * 64 + j * 16 + (lane & 15);
      int slot = (kc * 4 + (lane >> 4)) ^ (row & 7);
      bfr[j][kc] = *(const bf16x8*)&Bs[row * 128 + slot * 8];
    }

  f32x4 acc[4] = {};
  const u16* qbase = q + ((size_t)t0 + wr * 16 + (lane & 15)) * 4096 + (size_t)hgrp * 16 * 128 + (lane >> 4) * 8;
  int rbase = wr * 16 + ((lane >> 4) * 4);
  for (int h = 0; h < 16; h++){
    bf16x8 af[4];
    for (int kc = 0; kc < 4; kc++)
      af[kc] = *(const bf16x8*)&qbase[h * 128 + kc * 32];
    f32x4 ah[4] = {};
    for (int kc = 0; kc < 4; kc++)
      for (int j = 0; j < 4; j++)
        ah[j] = __builtin_amdgcn_mfma_f32_16x16x32_bf16(af[kc], bfr[j][kc], ah[j], 0, 0, 0);
    for (int r = 0; r < 4; r++){
      float wv = Ws[h][rbase + r];
      for (int j = 0; j < 4; j++)
        acc[j][r] += fmaxf(ah[j][r], 0.f) * wv;
    }
  }
  float* Sp = hgrp ? S1 : S0;
  for (int j = 0; j < 4; j++){
    int col = s0 + wc * 64 + j * 16 + (lane & 15);
    for (int r = 0; r < 4; r++)
      Sp[(size_t)(t0 + rbase + r) * 2048 + col] = acc[j][r];
  }
}

// ---------------- per-row top-K: sums partials, applies scale, synthesizes masked keys ----------------
__global__ __launch_bounds__(256) void k_topk(const float* __restrict__ S0, const float* __restrict__ S1,
                                              const int* __restrict__ ktp, const int* __restrict__ ksv,
                                              const int* __restrict__ ke, float* __restrict__ out){
  int t = blockIdx.x;
  int T = gridDim.x;
  const float* r0 = S0 + (size_t)t * 2048;
  const float* r1 = S1 + (size_t)t * 2048;
  __shared__ u32 keys[2048];
  __shared__ u32 hist[256];
  __shared__ u32 ssum[256];
  __shared__ u32 sb, srem;
  __shared__ u32 wtot[8];
  __shared__ int selIdx[256];
  __shared__ u32 baseGt, baseTie;
  __shared__ u64 skey[256];
  int tid = threadIdx.x;
  int K = ktp[0]; if (K > 256) K = 256;
  int ket = ke[t]; if (ket < 0) ket = 0; if (ket > 2048) ket = 2048;
  int kst = ksv[t]; if (kst < 0) kst = 0;
  int limit = (ket + 255) & ~255;
  if (limit < 256) limit = 256;
  if (limit > 2048) limit = 2048;
  const u32 kneg = fkey(-1e30f);
  const float scale = 0.015625f;  // 1/sqrt(D*H) = 1/64
  for (int i4 = tid; i4 < (limit >> 2); i4 += 256){
    int base = i4 * 4;
    float4 a = ((const float4*)r0)[i4];
    float4 b = ((const float4*)r1)[i4];
    float v0 = (a.x + b.x) * scale, v1 = (a.y + b.y) * scale;
    float v2 = (a.z + b.z) * scale, v3 = (a.w + b.w) * scale;
    keys[base + 0] = (base + 0 >= kst && base + 0 < ket) ? fkey(v0) : kneg;
    keys[base + 1] = (base + 1 >= kst && base + 1 < ket) ? fkey(v1) : kneg;
    keys[base + 2] = (base + 2 >= kst && base + 2 < ket) ? fkey(v2) : kneg;
    keys[base + 3] = (base + 3 >= kst && base + 3 < ket) ? fkey(v3) : kneg;
  }
  __syncthreads();
  if (limit > K){
    u32 prefix = 0, pmask = 0, rem = (u32)K;
    for (int p = 3; p >= 0; p--){
      int sh = p * 8;
      hist[tid] = 0;
      __syncthreads();
      for (int i = tid; i < limit; i += 256){
        u32 u = keys[i];
        if ((u & pmask) == prefix) atomicAdd(&hist[(u >> sh) & 255], 1u);
      }
      __syncthreads();
      ssum[tid] = hist[tid];
      __syncthreads();
      for (int off = 1; off < 256; off <<= 1){
        u32 add = (tid + off < 256) ? ssum[tid + off] : 0u;
        __syncthreads();
        ssum[tid] += add;
        __syncthreads();
      }
      u32 mine = ssum[tid];
      u32 above = (tid == 255) ? 0u : ssum[tid + 1];
      if (mine >= rem && above < rem){ sb = (u32)tid; srem = rem - above; }
      __syncthreads();
      prefix |= (sb << sh);
      pmask |= (255u << sh);
      rem = srem;
      __syncthreads();
    }
    u32 thr = prefix;
    int G = K - (int)rem;
    if (tid == 0){ baseGt = 0; baseTie = 0; }
    __syncthreads();
    int nch = limit >> 8;
    for (int ch = 0; ch < nch; ch++){
      int i = ch * 256 + tid;
      u32 u = keys[i];
      bool gt = (u > thr), tie = (u == thr);
      u64 bg = __ballot(gt), bt = __ballot(tie);
      int lane = tid & 63, w = tid >> 6;
      if (lane == 0){ wtot[w] = (u32)__popcll(bg); wtot[4 + w] = (u32)__popcll(bt); }
      __syncthreads();
      u32 og = baseGt, ot = baseTie;
      for (int ww = 0; ww < w; ww++){ og += wtot[ww]; ot += wtot[4 + ww]; }
      og += (u32)__popcll(bg & ((1ull << lane) - 1ull));
      ot += (u32)__popcll(bt & ((1ull << lane) - 1ull));
      if (gt) selIdx[og] = i;
      else if (tie && ot < rem) selIdx[G + ot] = i;
      __syncthreads();
      if (tid == 0){
        for (int ww = 0; ww < 4; ww++){ baseGt += wtot[ww]; baseTie += wtot[4 + ww]; }
      }
      __syncthreads();
    }
    if (tid < K){
      int si = selIdx[tid];
      u32 u = keys[si];
      skey[tid] = ((u64)(~u) << 32) | (u32)si;   // value desc, idx asc
    } else {
      skey[tid] = ~0ull;
    }
  } else {
    if (tid < K) skey[tid] = ((u64)(~keys[tid]) << 32) | (u32)tid;
    else skey[tid] = ~0ull;
  }
  __syncthreads();
  for (int size = 2; size <= 256; size <<= 1){
    for (int stride = size >> 1; stride > 0; stride >>= 1){
      int p = tid ^ stride;
      if (p > tid){
        bool up = ((tid & size) == 0);
        u64 a = skey[tid], b = skey[p];
        if ((a > b) == up){ skey[tid] = b; skey[p] = a; }
      }
      __syncthreads();
    }
  }
  if (tid < K){
    u64 sk = skey[tid];
    int idx = (int)(u32)(sk & 0xFFFFFFFFu);
    float val = unkey(~(u32)(sk >> 32));
    out[(size_t)t * K + tid] = (float)idx;                      // idx chunk (as float)
    out[(size_t)T * K + (size_t)t * K + tid] = val;             // values chunk
  }
}

extern "C" void kernel_launch(void* const* d_in, const int* in_sizes, int n_in,
                              void* d_out, int out_size, void* d_ws, size_t ws_size,
                              hipStream_t stream){
  const float* hs   = (const float*)d_in[0];
  const float* ql   = (const float*)d_in[1];
  const int*   ks   = (const int*)  d_in[2];
  const int*   ke   = (const int*)  d_in[3];
  const float* cosp = (const float*)d_in[4];
  const float* sinp = (const float*)d_in[5];
  const float* wqb  = (const float*)d_in[6];
  const float* wk   = (const float*)d_in[7];
  const float* kg   = (const float*)d_in[8];
  const float* kb   = (const float*)d_in[9];
  const float* wp   = (const float*)d_in[10];
  const int*   ktp  = (const int*)  d_in[11];

  char* w = (char*)d_ws;
  u16* qlb = (u16*)w;  w += (size_t)2048 * 1536 * 2;   // [0, 6.29MB)
  u16* wqT = (u16*)w;  w += (size_t)4096 * 1536 * 2;   // [6.29, 18.87MB)
  u16* wct = (u16*)w;  w += (size_t)192 * 4096 * 2;
  u16* qb  = (u16*)w;  w += (size_t)2048 * 4096 * 2;
  float* kwp = (float*)w; w += (size_t)8 * 2048 * 192 * 4;
  float* wfin = (float*)w; w += (size_t)2048 * 32 * 4;
  u16* krt = (u16*)w;  w += (size_t)2048 * 128 * 2;
  float* S0 = (float*)w; w += (size_t)2048 * 2048 * 4;
  int* list = (int*)w;  w += 2048 * 4;
  // S1 aliases qlb+wqT (16.78MB <= 18.87MB): lifetime-disjoint — gemm_fused finishes
  // reading qlb/wqT before k_scores writes S1; cvt/tcvt rewrite them next call.
  float* S1 = (float*)d_ws;

  hipLaunchKernelGGL(k_init, dim3(1), dim3(256), 0, stream, ke, list);
  hipLaunchKernelGGL(k_cvt, dim3(1536), dim3(256), 0, stream, ql, qlb, 393216);
  hipLaunchKernelGGL(k_tcvt, dim3(128, 48), dim3(256), 0, stream, wqb, wqT, 1536, 4096);
  hipLaunchKernelGGL(k_wct, dim3(6, 128), dim3(256), 0, stream, wk, wp, wct);
  hipLaunchKernelGGL(k_gemm_fused, dim3(896), dim3(256), 0, stream,
                     qlb, wqT, cosp, sinp, qb, hs, wct, kwp);
  hipLaunchKernelGGL(k_lnrope, dim3(512), dim3(256), 0, stream, kwp, kg, kb, cosp, sinp, krt, wfin);
  hipLaunchKernelGGL(k_scores, dim3(2048), dim3(256), 0, stream, qb, krt, wfin, list, S0, S1);
  hipLaunchKernelGGL(k_topk, dim3(2048), dim3(256), 0, stream, S0, S1, ktp, ks, ke, (float*)d_out);
}

// Round 21
// 147.223 us; speedup vs baseline: 1.7514x; 1.0510x over previous
//
#include <hip/hip_runtime.h>
#include <cstdint>

typedef unsigned short u16;
typedef unsigned int   u32;
typedef unsigned long long u64;

typedef short bf16x8 __attribute__((ext_vector_type(8)));
typedef float f32x4  __attribute__((ext_vector_type(4)));
typedef u16   u16x8  __attribute__((ext_vector_type(8)));

__device__ __forceinline__ u16 f2b(float f){
  u32 u = __float_as_uint(f);
  u += 0x7FFFu + ((u >> 16) & 1u);
  return (u16)(u >> 16);
}
__device__ __forceinline__ float b2f(u16 h){ return __uint_as_float(((u32)h) << 16); }
__device__ __forceinline__ u32 fkey(float f){
  u32 u = __float_as_uint(f);
  return u ^ ((u & 0x80000000u) ? 0xFFFFFFFFu : 0x80000000u);
}
__device__ __forceinline__ float unkey(u32 k){
  u32 u = (k & 0x80000000u) ? (k ^ 0x80000000u) : ~k;
  return __uint_as_float(u);
}
__device__ __forceinline__ void gload16(const void* g, void* l){
  __builtin_amdgcn_global_load_lds(
      reinterpret_cast<const __attribute__((address_space(1))) char*>(reinterpret_cast<uintptr_t>(g)),
      reinterpret_cast<__attribute__((address_space(3))) char*>(reinterpret_cast<uintptr_t>(l)),
      16, 0, 0);
}

// ---------------- fused prep: [0,1536) cvt ql; [1536,7680) tcvt wqb; [7680,8448) wct; 8448 init ----------------
__global__ __launch_bounds__(256) void k_prep(const float* __restrict__ ql, u16* __restrict__ qlb,
                                              const float* __restrict__ wqb, u16* __restrict__ wqT,
                                              const float* __restrict__ wk, const float* __restrict__ wp,
                                              u16* __restrict__ wct,
                                              const int* __restrict__ ke, int* __restrict__ list){
  __shared__ float tile[32][33];
  int b = blockIdx.x;
  int tid = threadIdx.x;
  if (b < 1536){
    // cvt: ql f32 -> qlb bf16 (8 elems/thread), n8 = 393216
    int i = b * 256 + tid;
    const float4* p = (const float4*)ql + (size_t)i * 2;
    float4 a = p[0], c = p[1];
    u16x8 v;
    v[0]=f2b(a.x); v[1]=f2b(a.y); v[2]=f2b(a.z); v[3]=f2b(a.w);
    v[4]=f2b(c.x); v[5]=f2b(c.y); v[6]=f2b(c.z); v[7]=f2b(c.w);
    *((u16x8*)qlb + i) = v;
  } else if (b < 7680){
    // tcvt: wqT[c][r] = bf16(wqb[r][c]), R=1536, C=4096
    int t = b - 1536;
    int c0 = (t & 127) * 32, r0 = (t >> 7) * 32;
    int tx = tid & 31, ty = tid >> 5;
    for (int i = 0; i < 4; i++){
      int r = ty * 4 + i;
      tile[r][tx] = wqb[(size_t)(r0 + r) * 4096 + c0 + tx];
    }
    __syncthreads();
    for (int i = 0; i < 4; i++){
      int c = ty * 4 + i;
      wqT[(size_t)(c0 + c) * 1536 + r0 + tx] = f2b(tile[tx][c]);
    }
  } else if (b < 8448){
    // wct: out[c][i], c<128 from wk, 128..159 from w_proj, pad 0
    int t = b - 7680;
    int c0 = (t % 6) * 32, i0 = (t / 6) * 32;
    int tx = tid & 31, ty = tid >> 5;
    for (int j = 0; j < 4; j++){
      int i = i0 + ty * 4 + j;
      int c = c0 + tx;
      float v = 0.f;
      if (c < 128) v = wk[(size_t)i * 128 + c];
      else if (c < 160) v = wp[(size_t)i * 32 + (c - 128)];
      tile[ty * 4 + j][tx] = v;
    }
    __syncthreads();
    for (int j = 0; j < 4; j++){
      int c = c0 + ty * 4 + j;
      wct[(size_t)c * 4096 + i0 + tx] = f2b(tile[tx][ty * 4 + j]);
    }
  } else {
    // init: per-t-tile kemax + compacted per-XCD work list
    __shared__ int km[64];
    if (tid < 64){
      int m = 0;
      for (int j = 0; j < 32; j++) m = max(m, ke[tid * 32 + j]);
      km[tid] = m;
    }
    __syncthreads();
    if (tid < 8){
      int x = tid, n = 0;
      for (int j0 = 0; j0 < 8; j0++){
        int tb = j0 * 8 + x;
        int kmax = km[tb];
        for (int sb = 0; sb < 16; sb++){
          if (sb * 128 < kmax){
            list[n * 8 + x] = tb * 32 + sb * 2 + 0; n++;
            list[n * 8 + x] = tb * 32 + sb * 2 + 1; n++;
          }
        }
      }
      for (; n < 256; n++) list[n * 8 + x] = -1;
    }
  }
}

// ---------------- fused GEMMs: blocks 0..511 = gemm_q (+RoPE); blocks 512..895 = gemm_kw ----------------
__global__ __launch_bounds__(256) void k_gemm_fused(const u16* __restrict__ Aq, const u16* __restrict__ Bq,
                                                    const float* __restrict__ cosp, const float* __restrict__ sinp,
                                                    u16* __restrict__ Cq,
                                                    const float* __restrict__ Akw, const u16* __restrict__ Bkw,
                                                    float* __restrict__ Cp){
  __shared__ char smem[40960];     // union: q = 16K+16K; kw = 32K+8K
  int tid = threadIdx.x, lane = tid & 63, wid = tid >> 6;
  if (blockIdx.x < 512){
    // ---- gemm_q body (R14-proven) ----
    const int N = 4096, Kd = 1536;
    u16* As = (u16*)smem;
    u16* Bs = (u16*)(smem + 16384);
    int linb = blockIdx.x;
    int xcd = linb & 7, loc = linb >> 3;
    int n0 = (xcd * 4 + (loc >> 4)) * 128;
    int m0 = (loc & 15) * 128;
    int wm = (wid >> 1) * 64, wn = (wid & 1) * 64;
    f32x4 acc[4][4] = {};
    for (int kt = 0; kt < Kd; kt += 64){
      for (int c = tid; c < 1024; c += 256){
        int row = c >> 3, slot = (c & 7) ^ (row & 7);
        gload16(Aq + (size_t)(m0 + row) * Kd + kt + slot * 8, As + (size_t)c * 8);
        gload16(Bq + (size_t)(n0 + row) * Kd + kt + slot * 8, Bs + (size_t)c * 8);
      }
      __syncthreads();
      for (int kk = 0; kk < 2; kk++){
        bf16x8 af[4], bfr[4];
        for (int i = 0; i < 4; i++){
          int rowa = wm + i * 16 + (lane & 15);
          int rowb = wn + i * 16 + (lane & 15);
          int sa = (kk * 4 + (lane >> 4)) ^ (rowa & 7);
          int sbx = (kk * 4 + (lane >> 4)) ^ (rowb & 7);
          af[i]  = *(const bf16x8*)&As[rowa * 64 + sa * 8];
          bfr[i] = *(const bf16x8*)&Bs[rowb * 64 + sbx * 8];
        }
        for (int i = 0; i < 4; i++)
          for (int j = 0; j < 4; j++)
            acc[i][j] = __builtin_amdgcn_mfma_f32_16x16x32_bf16(af[i], bfr[j], acc[i][j], 0, 0, 0);
      }
      __syncthreads();
    }
    if (wn == 0){
      int l = lane & 15;
      int base = lane & 48;
      int sl = base + ((2 * l) & 15);
      for (int i = 0; i < 4; i++){
        int rowb = m0 + wm + i * 16 + ((lane >> 4) * 4);
        f32x4 ne[4];
        for (int j = 0; j < 4; j++){
          int jj = j & 1;
          for (int r = 0; r < 4; r++){
            float eA = __shfl(acc[i][2 * jj][r],     sl);
            float eB = __shfl(acc[i][2 * jj + 1][r], sl);
            float oA = __shfl(acc[i][2 * jj][r],     sl + 1);
            float oB = __shfl(acc[i][2 * jj + 1][r], sl + 1);
            float e = (l >= 8) ? eB : eA;
            float o = (l >= 8) ? oB : oA;
            int row = rowb + r;
            int d = j * 16 + l;
            float c = cosp[(size_t)row * 64 + d];
            float s = sinp[(size_t)row * 64 + d];
            ne[j][r] = (j < 2) ? (e * c - o * s) : (o * c + e * s);
          }
        }
        for (int j = 0; j < 4; j++) acc[i][j] = ne[j];
      }
    }
    for (int i = 0; i < 4; i++)
      for (int j = 0; j < 4; j++){
        int row = m0 + wm + i * 16 + ((lane >> 4) * 4);
        int col = n0 + wn + j * 16 + (lane & 15);
        for (int r = 0; r < 4; r++)
          Cq[(size_t)(row + r) * N + col] = f2b(acc[i][j][r]);
      }
  } else {
    // ---- gemm_kw body (R14-proven); lin = blockIdx.x - 512 (512 % 8 == 0 keeps XCD mapping) ----
    const int Kd = 4096, NC = 192;
    float* As = (float*)smem;
    u16* Bs = (u16*)(smem + 32768);
    int lin = blockIdx.x - 512;
    int xcd = lin & 7, idx = lin >> 3;
    int nb = idx % 3, pz = idx / 3;
    int p = xcd + 8 * pz;
    int m0 = (p & 15) * 128;
    int kt0 = (p >> 4) * 512;
    int n0 = nb * 64;
    float* C = Cp + (size_t)(p >> 4) * 2048 * NC;
    int wm = wid * 32;
    f32x4 acc[2][4] = {};
    for (int kt = kt0; kt < kt0 + 512; kt += 64){
      for (int c = tid; c < 2048; c += 256){
        int row = c >> 4, slot = (c & 15) ^ (row & 7);
        gload16(Akw + (size_t)(m0 + row) * Kd + kt + slot * 4, As + (size_t)c * 4);
      }
      for (int c = tid; c < 512; c += 256){
        int row = c >> 3, slot = (c & 7) ^ (row & 7);
        gload16(Bkw + (size_t)(n0 + row) * Kd + kt + slot * 8, Bs + (size_t)c * 8);
      }
      __syncthreads();
      for (int kk = 0; kk < 2; kk++){
        bf16x8 af[2], bfr[4];
        for (int i = 0; i < 2; i++){
          int row = wm + i * 16 + (lane & 15);
          int c0 = kk * 8 + (lane >> 4) * 2;
          f32x4 lo = *(const f32x4*)&As[row * 64 + ((c0)     ^ (row & 7)) * 4];
          f32x4 hi = *(const f32x4*)&As[row * 64 + ((c0 + 1) ^ (row & 7)) * 4];
          bf16x8 t;
          t[0]=(short)f2b(lo[0]); t[1]=(short)f2b(lo[1]); t[2]=(short)f2b(lo[2]); t[3]=(short)f2b(lo[3]);
          t[4]=(short)f2b(hi[0]); t[5]=(short)f2b(hi[1]); t[6]=(short)f2b(hi[2]); t[7]=(short)f2b(hi[3]);
          af[i] = t;
        }
        for (int j = 0; j < 4; j++){
          int row = j * 16 + (lane & 15);
          int slot = (kk * 4 + (lane >> 4)) ^ (row & 7);
          bfr[j] = *(const bf16x8*)&Bs[row * 64 + slot * 8];
        }
        for (int i = 0; i < 2; i++)
          for (int j = 0; j < 4; j++)
            acc[i][j] = __builtin_amdgcn_mfma_f32_16x16x32_bf16(af[i], bfr[j], acc[i][j], 0, 0, 0);
      }
      __syncthreads();
    }
    for (int i = 0; i < 2; i++)
      for (int j = 0; j < 4; j++){
        int row = m0 + wm + i * 16 + ((lane >> 4) * 4);
        int col = n0 + j * 16 + (lane & 15);
        for (int r = 0; r < 4; r++)
          C[(size_t)(row + r) * NC + col] = acc[i][j][r];
      }
  }
}

// ---------------- reduce partials + LayerNorm + RoPE -> krot bf16; also wfin[2048][32] f32 ----------------
__global__ __launch_bounds__(256) void k_lnrope(const float* __restrict__ kwp, const float* __restrict__ gamma,
                                                const float* __restrict__ beta, const float* __restrict__ cosp,
                                                const float* __restrict__ sinp, u16* __restrict__ krot,
                                                float* __restrict__ wfin){
  const size_t ZS = (size_t)2048 * 192;
  int row = blockIdx.x * 4 + (threadIdx.x >> 6);
  int lane = threadIdx.x & 63;
  const float* x = kwp + (size_t)row * 192;
  float2 v = {0.f, 0.f};
  for (int z = 0; z < 8; z++){
    float2 p = *(const float2*)&x[z * ZS + lane * 2];
    v.x += p.x; v.y += p.y;
  }
  float s = v.x + v.y, ss = v.x * v.x + v.y * v.y;
  for (int o = 32; o; o >>= 1){ s += __shfl_xor(s, o); ss += __shfl_xor(ss, o); }
  float mu = s * (1.f / 128.f);
  float var = ss * (1.f / 128.f) - mu * mu;
  float rs = rsqrtf(var + 1e-6f);
  float y0 = (v.x - mu) * rs * gamma[lane * 2]     + beta[lane * 2];
  float y1 = (v.y - mu) * rs * gamma[lane * 2 + 1] + beta[lane * 2 + 1];
  u16* out = krot + (size_t)row * 128;
  if (lane < 32){
    float c = cosp[(size_t)row * 64 + lane], sn = sinp[(size_t)row * 64 + lane];
    out[lane]      = f2b(y0 * c - y1 * sn);
    out[lane + 32] = f2b(y1 * c + y0 * sn);
    float wsum = 0.f;
    for (int z = 0; z < 8; z++) wsum += x[z * ZS + 128 + lane];
    wfin[(size_t)row * 32 + lane] = wsum;
  } else {
    out[lane * 2]     = f2b(y0);
    out[lane * 2 + 1] = f2b(y1);
  }
}

// ---------------- scores v14: static compacted list + swizzled Bs (best measured) ----------------
__global__ __launch_bounds__(256, 4) void k_scores(const u16* __restrict__ q, const u16* __restrict__ krot,
                                                   const float* __restrict__ wfin, const int* __restrict__ list,
                                                   float* __restrict__ S0, float* __restrict__ S1){
  __shared__ u16 Bs[128 * 128];     // krot panel (32KB); 16B slot ^= row&7
  __shared__ float Ws[16][32];      // Ws[h][r] for this head group
  int e = list[blockIdx.x];
  if (e < 0) return;
  int tb = e >> 5, sb = (e >> 1) & 15, hgrp = e & 1;
  int t0 = tb * 32, s0 = sb * 128;
  int tid = threadIdx.x, lane = tid & 63, wid = tid >> 6;
  int wr = wid >> 1, wc = wid & 1;  // wave = 16(t) x 64(s) subtile

  for (int c = tid; c < 2048; c += 256){
    int row = c >> 4, slot = (c & 15) ^ (row & 7);
    gload16(krot + (size_t)(s0 + row) * 128 + slot * 8, (u16*)Bs + (size_t)c * 8);
  }
  for (int i = tid; i < 512; i += 256){
    int h = i >> 5, r = i & 31;
    Ws[h][r] = wfin[(size_t)(t0 + r) * 32 + hgrp * 16 + h];
  }
  __syncthreads();

  // hoist B fragments (head-invariant): 16 x b128, one-time swizzled LDS reads
  bf16x8 bfr[4][4];
  for (int j = 0; j < 4; j++)
    for (int kc = 0; kc < 4; kc++){
      int row = wc * 64 + j * 16 + (lane & 15);
      int slot = (kc * 4 + (lane >> 4)) ^ (row & 7);
      bfr[j][kc] = *(const bf16x8*)&Bs[row * 128 + slot * 8];
    }

  f32x4 acc[4] = {};
  const u16* qbase = q + ((size_t)t0 + wr * 16 + (lane & 15)) * 4096 + (size_t)hgrp * 16 * 128 + (lane >> 4) * 8;
  int rbase = wr * 16 + ((lane >> 4) * 4);
  for (int h = 0; h < 16; h++){
    bf16x8 af[4];
    for (int kc = 0; kc < 4; kc++)
      af[kc] = *(const bf16x8*)&qbase[h * 128 + kc * 32];
    f32x4 ah[4] = {};
    for (int kc = 0; kc < 4; kc++)
      for (int j = 0; j < 4; j++)
        ah[j] = __builtin_amdgcn_mfma_f32_16x16x32_bf16(af[kc], bfr[j][kc], ah[j], 0, 0, 0);
    for (int r = 0; r < 4; r++){
      float wv = Ws[h][rbase + r];
      for (int j = 0; j < 4; j++)
        acc[j][r] += fmaxf(ah[j][r], 0.f) * wv;
    }
  }
  float* Sp = hgrp ? S1 : S0;
  for (int j = 0; j < 4; j++){
    int col = s0 + wc * 64 + j * 16 + (lane & 15);
    for (int r = 0; r < 4; r++)
      Sp[(size_t)(t0 + rbase + r) * 2048 + col] = acc[j][r];
  }
}

// ---------------- per-row top-K: sums partials, applies scale, synthesizes masked keys ----------------
__global__ __launch_bounds__(256) void k_topk(const float* __restrict__ S0, const float* __restrict__ S1,
                                              const int* __restrict__ ktp, const int* __restrict__ ksv,
                                              const int* __restrict__ ke, float* __restrict__ out){
  int t = blockIdx.x;
  int T = gridDim.x;
  const float* r0 = S0 + (size_t)t * 2048;
  const float* r1 = S1 + (size_t)t * 2048;
  __shared__ u32 keys[2048];
  __shared__ u32 hist[256];
  __shared__ u32 ssum[256];
  __shared__ u32 sb, srem;
  __shared__ u32 wtot[8];
  __shared__ int selIdx[256];
  __shared__ u32 baseGt, baseTie;
  __shared__ u64 skey[256];
  int tid = threadIdx.x;
  int K = ktp[0]; if (K > 256) K = 256;
  int ket = ke[t]; if (ket < 0) ket = 0; if (ket > 2048) ket = 2048;
  int kst = ksv[t]; if (kst < 0) kst = 0;
  int limit = (ket + 255) & ~255;
  if (limit < 256) limit = 256;
  if (limit > 2048) limit = 2048;
  const u32 kneg = fkey(-1e30f);
  const float scale = 0.015625f;  // 1/sqrt(D*H) = 1/64
  for (int i4 = tid; i4 < (limit >> 2); i4 += 256){
    int base = i4 * 4;
    float4 a = ((const float4*)r0)[i4];
    float4 b = ((const float4*)r1)[i4];
    float v0 = (a.x + b.x) * scale, v1 = (a.y + b.y) * scale;
    float v2 = (a.z + b.z) * scale, v3 = (a.w + b.w) * scale;
    keys[base + 0] = (base + 0 >= kst && base + 0 < ket) ? fkey(v0) : kneg;
    keys[base + 1] = (base + 1 >= kst && base + 1 < ket) ? fkey(v1) : kneg;
    keys[base + 2] = (base + 2 >= kst && base + 2 < ket) ? fkey(v2) : kneg;
    keys[base + 3] = (base + 3 >= kst && base + 3 < ket) ? fkey(v3) : kneg;
  }
  __syncthreads();
  if (limit > K){
    u32 prefix = 0, pmask = 0, rem = (u32)K;
    for (int p = 3; p >= 0; p--){
      int sh = p * 8;
      hist[tid] = 0;
      __syncthreads();
      for (int i = tid; i < limit; i += 256){
        u32 u = keys[i];
        if ((u & pmask) == prefix) atomicAdd(&hist[(u >> sh) & 255], 1u);
      }
      __syncthreads();
      ssum[tid] = hist[tid];
      __syncthreads();
      for (int off = 1; off < 256; off <<= 1){
        u32 add = (tid + off < 256) ? ssum[tid + off] : 0u;
        __syncthreads();
        ssum[tid] += add;
        __syncthreads();
      }
      u32 mine = ssum[tid];
      u32 above = (tid == 255) ? 0u : ssum[tid + 1];
      if (mine >= rem && above < rem){ sb = (u32)tid; srem = rem - above; }
      __syncthreads();
      prefix |= (sb << sh);
      pmask |= (255u << sh);
      rem = srem;
      __syncthreads();
    }
    u32 thr = prefix;
    int G = K - (int)rem;
    if (tid == 0){ baseGt = 0; baseTie = 0; }
    __syncthreads();
    int nch = limit >> 8;
    for (int ch = 0; ch < nch; ch++){
      int i = ch * 256 + tid;
      u32 u = keys[i];
      bool gt = (u > thr), tie = (u == thr);
      u64 bg = __ballot(gt), bt = __ballot(tie);
      int lane = tid & 63, w = tid >> 6;
      if (lane == 0){ wtot[w] = (u32)__popcll(bg); wtot[4 + w] = (u32)__popcll(bt); }
      __syncthreads();
      u32 og = baseGt, ot = baseTie;
      for (int ww = 0; ww < w; ww++){ og += wtot[ww]; ot += wtot[4 + ww]; }
      og += (u32)__popcll(bg & ((1ull << lane) - 1ull));
      ot += (u32)__popcll(bt & ((1ull << lane) - 1ull));
      if (gt) selIdx[og] = i;
      else if (tie && ot < rem) selIdx[G + ot] = i;
      __syncthreads();
      if (tid == 0){
        for (int ww = 0; ww < 4; ww++){ baseGt += wtot[ww]; baseTie += wtot[4 + ww]; }
      }
      __syncthreads();
    }
    if (tid < K){
      int si = selIdx[tid];
      u32 u = keys[si];
      skey[tid] = ((u64)(~u) << 32) | (u32)si;   // value desc, idx asc
    } else {
      skey[tid] = ~0ull;
    }
  } else {
    if (tid < K) skey[tid] = ((u64)(~keys[tid]) << 32) | (u32)tid;
    else skey[tid] = ~0ull;
  }
  __syncthreads();
  for (int size = 2; size <= 256; size <<= 1){
    for (int stride = size >> 1; stride > 0; stride >>= 1){
      int p = tid ^ stride;
      if (p > tid){
        bool up = ((tid & size) == 0);
        u64 a = skey[tid], b = skey[p];
        if ((a > b) == up){ skey[tid] = b; skey[p] = a; }
      }
      __syncthreads();
    }
  }
  if (tid < K){
    u64 sk = skey[tid];
    int idx = (int)(u32)(sk & 0xFFFFFFFFu);
    float val = unkey(~(u32)(sk >> 32));
    out[(size_t)t * K + tid] = (float)idx;                      // idx chunk (as float)
    out[(size_t)T * K + (size_t)t * K + tid] = val;             // values chunk
  }
}

extern "C" void kernel_launch(void* const* d_in, const int* in_sizes, int n_in,
                              void* d_out, int out_size, void* d_ws, size_t ws_size,
                              hipStream_t stream){
  const float* hs   = (const float*)d_in[0];
  const float* ql   = (const float*)d_in[1];
  const int*   ks   = (const int*)  d_in[2];
  const int*   ke   = (const int*)  d_in[3];
  const float* cosp = (const float*)d_in[4];
  const float* sinp = (const float*)d_in[5];
  const float* wqb  = (const float*)d_in[6];
  const float* wk   = (const float*)d_in[7];
  const float* kg   = (const float*)d_in[8];
  const float* kb   = (const float*)d_in[9];
  const float* wp   = (const float*)d_in[10];
  const int*   ktp  = (const int*)  d_in[11];

  char* w = (char*)d_ws;
  u16* qlb = (u16*)w;  w += (size_t)2048 * 1536 * 2;   // [0, 6.29MB)
  u16* wqT = (u16*)w;  w += (size_t)4096 * 1536 * 2;   // [6.29, 18.87MB)
  u16* wct = (u16*)w;  w += (size_t)192 * 4096 * 2;
  u16* qb  = (u16*)w;  w += (size_t)2048 * 4096 * 2;
  float* kwp = (float*)w; w += (size_t)8 * 2048 * 192 * 4;
  float* wfin = (float*)w; w += (size_t)2048 * 32 * 4;
  u16* krt = (u16*)w;  w += (size_t)2048 * 128 * 2;
  float* S0 = (float*)w; w += (size_t)2048 * 2048 * 4;
  int* list = (int*)w;  w += 2048 * 4;
  // S1 aliases qlb+wqT (16.78MB <= 18.87MB): lifetime-disjoint — gemm_fused finishes
  // reading qlb/wqT before k_scores writes S1; k_prep rewrites them next call.
  float* S1 = (float*)d_ws;

  hipLaunchKernelGGL(k_prep, dim3(8449), dim3(256), 0, stream, ql, qlb, wqb, wqT, wk, wp, wct, ke, list);
  hipLaunchKernelGGL(k_gemm_fused, dim3(896), dim3(256), 0, stream,
                     qlb, wqT, cosp, sinp, qb, hs, wct, kwp);
  hipLaunchKernelGGL(k_lnrope, dim3(512), dim3(256), 0, stream, kwp, kg, kb, cosp, sinp, krt, wfin);
  hipLaunchKernelGGL(k_scores, dim3(2048), dim3(256), 0, stream, qb, krt, wfin, list, S0, S1);
  hipLaunchKernelGGL(k_topk, dim3(2048), dim3(256), 0, stream, S0, S1, ktp, ks, ke, (float*)d_out);
}